// Round 17
// baseline (224.093 us; speedup 1.0000x reference)
//
#include <hip/hip_runtime.h>

// Frame-wise E^H D E exact NDFT via separable phasors as two complex GEMMs on
// fp16 matrix cores (fp32 accumulate).
// v18 = v15 (217.9us best) with:
//  - v17 Ts swizzle REVERTED (SQ_LDS_BANK_CONFLICT proved structural: exactly
//    ~3.4cy x #b128-ops in every variant, immune to swizzle; swizzle cost
//    +1.5us of address VALU).
//  - g relaid out [t][c][k]: adj build g-loads become 2x float4 contiguous
//    (was 4x 8B at 64B stride) with 8-lane broadcast; fwd epilogue g-write
//    becomes contiguous. Strictly fewer instructions + transactions.
//  - fwd __launch_bounds__(256,4): cap VGPR at 128 (live ~103, no spill risk)
//    so register drift can't cost a residency slot.

#define NT 16
#define NK 2048
#define NXY 128
#define NC 8

typedef _Float16 f16x8 __attribute__((ext_vector_type(8)));
typedef float f32x4 __attribute__((ext_vector_type(4)));

union F8 { f16x8 h; uint u[4]; };

#define MFMA16(a, b, c) __builtin_amdgcn_mfma_f32_16x16x32_f16((a), (b), (c), 0, 0, 0)

__device__ __forceinline__ uint pack2h(float a, float b) {
    union { _Float16 h[2]; uint u; } p;
    p.h[0] = (_Float16)a; p.h[1] = (_Float16)b;
    return p.u;
}
__device__ __forceinline__ float2 unpack2h(uint v) {
    union { uint u; _Float16 h[2]; } p;
    p.u = v;
    return make_float2((float)p.h[0], (float)p.h[1]);
}
__device__ __forceinline__ uint rot16(uint v) { return (v >> 16) | (v << 16); }

// ---------------------------------------------------------------------------
// prep_all: fused preps, branch on block range (block-uniform divergence).
//  [0, 16384):      phasA -> tiled ExC [t][kt16][xc8][kp128][xq16] + linear
//                   EyL [t][k][y]
//  [16384, 32768):  phasB -> ExT [t][x][k]
//  [32768, 40960):  src   -> srcB fragment order [t][c][ch8][mf8][r16][xl16]
// ---------------------------------------------------------------------------
__global__ __launch_bounds__(256) void prep_all(const float* __restrict__ ktraj,
                                                const float* __restrict__ xin,
                                                const float* __restrict__ csmap,
                                                uint* __restrict__ ExC,
                                                uint* __restrict__ ExT,
                                                uint* __restrict__ EyL,
                                                uint* __restrict__ srcB) {
    const int b = blockIdx.x;
    const int tid = threadIdx.x;
    if (b < 16384) {
        // ---- phasA ----
        const int t = b >> 10;
        const int k = (b & 1023) * 2 + (tid >> 7);
        const int x = tid & 127;
        const float kx = ktraj[(size_t)k * NT + t];
        const float ky = ktraj[(size_t)(NK + k) * NT + t];
        const float xm = (float)(x - 64);
        float s, c;
        __sincosf(-kx * xm, &s, &c);
        ExC[((size_t)(t * 16 + (k >> 7)) * 8 + (x >> 4)) * 2048 +
            (size_t)(k & 127) * 16 + (x & 15)] = pack2h(c, s);
        __sincosf(-ky * xm, &s, &c);
        EyL[((size_t)t * NK + k) * NXY + x] = pack2h(c, s);
    } else if (b < 32768) {
        // ---- phasB ----
        const int q = b - 16384;
        const int t = q >> 10, x = (q >> 3) & 127, kz = q & 7;
        const int k = kz * 256 + tid;
        const float kx = ktraj[(size_t)k * NT + t];
        float s, c;
        __sincosf(-kx * (float)(x - 64), &s, &c);
        ExT[((size_t)t * NXY + x) * NK + k] = pack2h(c, s);
    } else {
        // ---- src ----
        const int idx = (b - 32768) * 256 + tid;   // < 2^21
        const int t = idx & 15, r = (idx >> 4) & 15, xl = (idx >> 8) & 15,
                  mf = (idx >> 12) & 7, ch = (idx >> 15) & 7, c = idx >> 18;
        const int x = ch * 16 + xl, y = mf * 16 + r;
        const float ir = xin[(size_t)(x * NXY + y) * NT + t];
        const float ii = xin[(size_t)NXY * NXY * NT + (size_t)(x * NXY + y) * NT + t];
        const float sr = csmap[(size_t)c * 2 * NXY * NXY + x * NXY + y];
        const float si = csmap[(size_t)c * 2 * NXY * NXY + NXY * NXY + x * NXY + y];
        srcB[((size_t)(t * NC + c) << 14) + ch * 2048 + mf * 256 + r * 16 + xl] =
            pack2h(sr * ir - si * ii, sr * ii + si * ir);
    }
}

// ---------------------------------------------------------------------------
// fwd_gemm: block = (t, c, kt of 64 kpoints), 256 thr, 4 waves.  (v12 body)
// Wave ws owns kp slice [kt*64 + ws*16, +16) and ALL 8 mf rows. 1 B-load per
// chunk per wave, in-wave epilogue, B-side complex rotation.
// v18: g stored [t][c][k] (contiguous epilogue write); launch_bounds(256,4).
// ---------------------------------------------------------------------------
__global__ __launch_bounds__(256, 4) void fwd_gemm(const uint* __restrict__ ExC,
                                                   const uint* __restrict__ EyL,
                                                   const uint* __restrict__ srcB,
                                                   const float* __restrict__ dcomp,
                                                   float2* __restrict__ g) {
    const int t = blockIdx.x, c = blockIdx.y, kt = blockIdx.z;
    const int tid = threadIdx.x, lane = tid & 63, ws = tid >> 6;
    const int quad = lane >> 4, l15 = lane & 15;

    __shared__ __align__(16) _Float16 As[2][4096];

    f32x4 accr[8], acci[8];
#pragma unroll
    for (int mf = 0; mf < 8; ++mf) { accr[mf] = (f32x4)0.0f; acci[mf] = (f32x4)0.0f; }

    const uint* srcT = srcB + ((size_t)(t * NC + c) << 14);
    const uint* exB = ExC + (size_t)(t * 16 + (kt >> 1)) * 16384;
    const int kin0 = (kt & 1) * 64 + ws * 16;            // this wave's kp base (128-tile)

    // prologue: stage + B load for chunk 0
    F8 vA0 = *(const F8*)(srcT + tid * 8);
    F8 vA1 = *(const F8*)(srcT + tid * 8 + 4);
    F8 Bc = *(const F8*)(exB + (kin0 + l15) * 16 + quad * 4);

#pragma unroll 2
    for (int ch = 0; ch < 8; ++ch) {
        const int buf = ch & 1;
        *(F8*)&As[buf][tid * 16] = vA0;
        *(F8*)&As[buf][tid * 16 + 8] = vA1;
        __syncthreads();
        const int chn = ch < 7 ? ch + 1 : 7;
        vA0 = *(const F8*)(srcT + chn * 2048 + tid * 8);
        vA1 = *(const F8*)(srcT + chn * 2048 + tid * 8 + 4);
        F8 Bn = *(const F8*)(exB + chn * 2048 + (kin0 + l15) * 16 + quad * 4);
        __builtin_amdgcn_sched_barrier(0);
        // B-side rotation: Br = (bR,-bI) for real part, Bi = (bI,bR) for imag
        F8 Br, Bi;
#pragma unroll
        for (int d = 0; d < 4; ++d) {
            Br.u[d] = Bc.u[d] ^ 0x80000000u;
            Bi.u[d] = rot16(Bc.u[d]);
        }
#pragma unroll
        for (int mf = 0; mf < 8; ++mf) {
            F8 Ap = *(const F8*)&As[buf][mf * 512 + l15 * 32 + quad * 8];
            accr[mf] = MFMA16(Ap.h, Br.h, accr[mf]);
            acci[mf] = MFMA16(Ap.h, Bi.h, acci[mf]);
        }
        Bc = Bn;
    }

    // epilogue: in-wave y-reduction with EyL (all 8 mf), quad-reduce, store g
    const int kpoint = kt * 64 + ws * 16 + l15;
    const uint* eyRow = EyL + ((size_t)t * NK + kpoint) * NXY;
    float kdr = 0.f, kdi = 0.f;
#pragma unroll
    for (int mf = 0; mf < 8; ++mf) {
        F8 e4 = *(const F8*)(eyRow + mf * 16 + quad * 4);
#pragma unroll
        for (int rr = 0; rr < 4; ++rr) {
            float2 ey = unpack2h(e4.u[rr]);
            float cr = accr[mf][rr], ci = acci[mf][rr];
            kdr += ey.x * cr - ey.y * ci;
            kdi += ey.x * ci + ey.y * cr;
        }
    }
    kdr += __shfl_xor(kdr, 16); kdr += __shfl_xor(kdr, 32);
    kdi += __shfl_xor(kdi, 16); kdi += __shfl_xor(kdi, 32);
    if (lane < 16) {
        float w = dcomp[(size_t)kpoint * NT + t] * (1.0f / 16384.0f);
        g[(size_t)(t * NC + c) * NK + kpoint] = make_float2(kdr * w, kdi * w);
    }
}

// ---------------------------------------------------------------------------
// adj_gemm: block = (t, ytile of 8 y, kz of 2 k-halves), 512 thr (8 waves).
// Each block: K' = 2048 halves (1024 kpoints), 32 chunks of 32 kpoints.
// Disjoint reads, private f32 partials. Loop body v10/v12 VERBATIM except the
// g build loads: g[t][c][k] -> 2x float4 contiguous (8-lane broadcast rows).
// ---------------------------------------------------------------------------
__global__ __launch_bounds__(512) void adj_gemm(const uint* __restrict__ ExT,
                                                const uint* __restrict__ EyL,
                                                const float2* __restrict__ g,
                                                const float* __restrict__ csmap,
                                                float* __restrict__ part) {
    const int t = blockIdx.x, yt = blockIdx.y, kz = blockIdx.z, ybase = yt * 8;
    const int tid = threadIdx.x, lane = tid & 63, ws = tid >> 6;
    const int quad = lane >> 4, l15 = lane & 15;
    const int x = ws * 16 + l15;
    const int kbase = kz * 1024;

    __shared__ __align__(16) _Float16 Ts[2][64][72];    // 64 K'-halves + 8 pad

    f32x4 accr[4], acci[4];
#pragma unroll
    for (int mf = 0; mf < 4; ++mf) { accr[mf] = (f32x4)0.0f; acci[mf] = (f32x4)0.0f; }

    const uint* eyBase = EyL + (size_t)t * NK * NXY;
    const uint* exRow = ExT + (size_t)t * NXY * NK + (size_t)x * NK + kbase;

    const int bm = tid & 63;                 // build: row m
    const int bk4 = (tid >> 6) * 4;          // build: kpoint offset (0..28)
    const int by = ybase + (bm >> 3), bc = bm & 7;
    const float2* gRow = g + (size_t)(t * NC + bc) * NK;   // [k] contiguous

    // build chunk 0
    {
        const int kb = kbase + bk4;
        float4 ga = *(const float4*)(gRow + kb);
        float4 gb = *(const float4*)(gRow + kb + 2);
        F8 w; float2 e;
        e = unpack2h(eyBase[(size_t)(kb + 0) * NXY + by]);
        w.u[0] = pack2h(e.x*ga.x + e.y*ga.y, e.x*ga.y - e.y*ga.x);
        e = unpack2h(eyBase[(size_t)(kb + 1) * NXY + by]);
        w.u[1] = pack2h(e.x*ga.z + e.y*ga.w, e.x*ga.w - e.y*ga.z);
        e = unpack2h(eyBase[(size_t)(kb + 2) * NXY + by]);
        w.u[2] = pack2h(e.x*gb.x + e.y*gb.y, e.x*gb.y - e.y*gb.x);
        e = unpack2h(eyBase[(size_t)(kb + 3) * NXY + by]);
        w.u[3] = pack2h(e.x*gb.z + e.y*gb.w, e.x*gb.w - e.y*gb.z);
        *(F8*)&Ts[0][bm][bk4 * 2] = w;
    }
    __syncthreads();

    for (int ch = 0; ch < 32; ++ch) {
        const int buf = ch & 1;
        const int chn = ch < 31 ? ch + 1 : 31;       // clamped: last iter redundant
        // --- issue ALL global loads for this iteration up front ---
        const int kb = kbase + chn * 32 + bk4;
        float4 ga = *(const float4*)(gRow + kb);
        float4 gb = *(const float4*)(gRow + kb + 2);
        uint ev0 = eyBase[(size_t)(kb + 0) * NXY + by];
        uint ev1 = eyBase[(size_t)(kb + 1) * NXY + by];
        uint ev2 = eyBase[(size_t)(kb + 2) * NXY + by];
        uint ev3 = eyBase[(size_t)(kb + 3) * NXY + by];
        F8 Bf0 = *(const F8*)(exRow + ch * 32 + quad * 4);
        F8 Bf1 = *(const F8*)(exRow + ch * 32 + 16 + quad * 4);
        // B-side rotation for imag accumulator: Bi = (-bI, bR)
        F8 Bi0, Bi1;
#pragma unroll
        for (int d = 0; d < 4; ++d) {
            Bi0.u[d] = rot16(Bf0.u[d]) ^ 0x00008000u;
            Bi1.u[d] = rot16(Bf1.u[d]) ^ 0x00008000u;
        }
        // --- MFMA phase on Ts[buf] ---
#pragma unroll
        for (int mf = 0; mf < 4; ++mf) {
            F8 Ap0 = *(const F8*)&Ts[buf][mf * 16 + l15][quad * 8];
            accr[mf] = MFMA16(Ap0.h, Bf0.h, accr[mf]);
            acci[mf] = MFMA16(Ap0.h, Bi0.h, acci[mf]);
            F8 Ap1 = *(const F8*)&Ts[buf][mf * 16 + l15][32 + quad * 8];
            accr[mf] = MFMA16(Ap1.h, Bf1.h, accr[mf]);
            acci[mf] = MFMA16(Ap1.h, Bi1.h, acci[mf]);
        }
        // --- pack + write build for chunk ch+1 ---
        {
            F8 w; float2 e;
            e = unpack2h(ev0); w.u[0] = pack2h(e.x*ga.x + e.y*ga.y, e.x*ga.y - e.y*ga.x);
            e = unpack2h(ev1); w.u[1] = pack2h(e.x*ga.z + e.y*ga.w, e.x*ga.w - e.y*ga.z);
            e = unpack2h(ev2); w.u[2] = pack2h(e.x*gb.x + e.y*gb.y, e.x*gb.y - e.y*gb.x);
            e = unpack2h(ev3); w.u[3] = pack2h(e.x*gb.z + e.y*gb.w, e.x*gb.w - e.y*gb.z);
            *(F8*)&Ts[buf ^ 1][bm][bk4 * 2] = w;
        }
        __syncthreads();
    }

    // epilogue: coil-combine with conj(smap), write partial [kz][2][x][y][t]
    float* po = part + (size_t)kz * 2 * NXY * NXY * NT;
#pragma unroll
    for (int mf = 0; mf < 4; ++mf) {
        const int y = ybase + 2 * mf + (quad >> 1);
        float or_ = 0.f, oi_ = 0.f;
#pragma unroll
        for (int r = 0; r < 4; ++r) {
            int c = 4 * (quad & 1) + r;
            float sr = csmap[(size_t)c * 2 * NXY * NXY + x * NXY + y];
            float si = csmap[(size_t)c * 2 * NXY * NXY + NXY * NXY + x * NXY + y];
            float xr = accr[mf][r], xi = acci[mf][r];
            or_ += sr * xr + si * xi;
            oi_ += sr * xi - si * xr;
        }
        or_ += __shfl_xor(or_, 16);
        oi_ += __shfl_xor(oi_, 16);
        if ((lane & 16) == 0) {
            po[(size_t)(x * NXY + y) * NT + t] = or_;
            po[(size_t)NXY * NXY * NT + (size_t)(x * NXY + y) * NT + t] = oi_;
        }
    }
}

// ---------------------------------------------------------------------------
// combine: out = part0 + part1 (elementwise over 2*128*128*16 floats)
// ---------------------------------------------------------------------------
__global__ __launch_bounds__(256) void combine(const float* __restrict__ part,
                                               float* __restrict__ out) {
    const int idx = blockIdx.x * 256 + threadIdx.x;      // < 524288
    out[idx] = part[idx] + part[idx + 2 * NXY * NXY * NT];
}

// ---------------------------------------------------------------------------
extern "C" void kernel_launch(void* const* d_in, const int* in_sizes, int n_in,
                              void* d_out, int out_size, void* d_ws, size_t ws_size,
                              hipStream_t stream) {
    const float* xin   = (const float*)d_in[0];  // (2,128,128,16)
    const float* ktraj = (const float*)d_in[1];  // (2,2048,16)
    const float* csmap = (const float*)d_in[2];  // (8,2,128,128)
    const float* dcomp = (const float*)d_in[3];  // (2048,16)
    float* out = (float*)d_out;                  // (2,128,128,16)

    // ws layout: ExC + ExT + EyL (16MB each) + srcB 8MB + g 2MB + part 4MB = 62MB
    const size_t TBL = (size_t)NT * NK * NXY;            // 4.19M dwords per table
    uint* ExC  = (uint*)d_ws;                            // [t][kt][xc][kp][xq]
    uint* ExT  = ExC + TBL;                              // [t][x][k]
    uint* EyL  = ExT + TBL;                              // [t][k][y]
    uint* srcB = EyL + TBL;                              // fragment-ordered
    float2* g  = (float2*)(srcB + (size_t)NT * NC * NXY * NXY);  // [t][c][k]
    float* part = (float*)(g + (size_t)NT * NK * NC);    // [kz2][2][x][y][t]

    prep_all<<<dim3(40960), 256, 0, stream>>>(ktraj, xin, csmap, ExC, ExT, EyL, srcB);
    fwd_gemm<<<dim3(NT, NC, 32), 256, 0, stream>>>(ExC, EyL, srcB, dcomp, g);
    adj_gemm<<<dim3(NT, NXY / 8, 2), 512, 0, stream>>>(ExT, EyL, g, csmap, part);
    combine<<<dim3(2048), 256, 0, stream>>>(part, out);
}

// Round 18
// 211.340 us; speedup vs baseline: 1.0603x; 1.0603x over previous
//
#include <hip/hip_runtime.h>

// Frame-wise E^H D E exact NDFT via separable phasors as two complex GEMMs on
// fp16 matrix cores (fp32 accumulate).
// v19 = v15 (217.9us best) + ONE scheduling edit in adj:
//  - B-fragment loads issued FIRST in the load block (they are consumed first,
//    by the Bi rotation; vmcnt drains in-order so v15's B-last order forced a
//    full drain before the MFMA phase), then the 8 build loads, then
//    sched_barrier(0) (fwd-proven pin). MFMA phase starts at vmcnt(8);
//    build latency hides under the 16 MFMAs. Addressing per-element scalar
//    (v18's float4 "simplification" re-sank the pipeline -> reverted).
//  - fwd: __launch_bounds__(256,4) (cap 128 VGPR; live ~100; isolated change).
//  - g layout back to [t][k][c] (v15), partials kz=2, combine: v15 verbatim.

#define NT 16
#define NK 2048
#define NXY 128
#define NC 8

typedef _Float16 f16x8 __attribute__((ext_vector_type(8)));
typedef float f32x4 __attribute__((ext_vector_type(4)));

union F8 { f16x8 h; uint u[4]; };

#define MFMA16(a, b, c) __builtin_amdgcn_mfma_f32_16x16x32_f16((a), (b), (c), 0, 0, 0)

__device__ __forceinline__ uint pack2h(float a, float b) {
    union { _Float16 h[2]; uint u; } p;
    p.h[0] = (_Float16)a; p.h[1] = (_Float16)b;
    return p.u;
}
__device__ __forceinline__ float2 unpack2h(uint v) {
    union { uint u; _Float16 h[2]; } p;
    p.u = v;
    return make_float2((float)p.h[0], (float)p.h[1]);
}
__device__ __forceinline__ uint rot16(uint v) { return (v >> 16) | (v << 16); }

// ---------------------------------------------------------------------------
// prep_all: fused preps, branch on block range (block-uniform divergence).
//  [0, 16384):      phasA -> tiled ExC [t][kt16][xc8][kp128][xq16] + linear
//                   EyL [t][k][y]
//  [16384, 32768):  phasB -> ExT [t][x][k]
//  [32768, 40960):  src   -> srcB fragment order [t][c][ch8][mf8][r16][xl16]
// ---------------------------------------------------------------------------
__global__ __launch_bounds__(256) void prep_all(const float* __restrict__ ktraj,
                                                const float* __restrict__ xin,
                                                const float* __restrict__ csmap,
                                                uint* __restrict__ ExC,
                                                uint* __restrict__ ExT,
                                                uint* __restrict__ EyL,
                                                uint* __restrict__ srcB) {
    const int b = blockIdx.x;
    const int tid = threadIdx.x;
    if (b < 16384) {
        // ---- phasA ----
        const int t = b >> 10;
        const int k = (b & 1023) * 2 + (tid >> 7);
        const int x = tid & 127;
        const float kx = ktraj[(size_t)k * NT + t];
        const float ky = ktraj[(size_t)(NK + k) * NT + t];
        const float xm = (float)(x - 64);
        float s, c;
        __sincosf(-kx * xm, &s, &c);
        ExC[((size_t)(t * 16 + (k >> 7)) * 8 + (x >> 4)) * 2048 +
            (size_t)(k & 127) * 16 + (x & 15)] = pack2h(c, s);
        __sincosf(-ky * xm, &s, &c);
        EyL[((size_t)t * NK + k) * NXY + x] = pack2h(c, s);
    } else if (b < 32768) {
        // ---- phasB ----
        const int q = b - 16384;
        const int t = q >> 10, x = (q >> 3) & 127, kz = q & 7;
        const int k = kz * 256 + tid;
        const float kx = ktraj[(size_t)k * NT + t];
        float s, c;
        __sincosf(-kx * (float)(x - 64), &s, &c);
        ExT[((size_t)t * NXY + x) * NK + k] = pack2h(c, s);
    } else {
        // ---- src ----
        const int idx = (b - 32768) * 256 + tid;   // < 2^21
        const int t = idx & 15, r = (idx >> 4) & 15, xl = (idx >> 8) & 15,
                  mf = (idx >> 12) & 7, ch = (idx >> 15) & 7, c = idx >> 18;
        const int x = ch * 16 + xl, y = mf * 16 + r;
        const float ir = xin[(size_t)(x * NXY + y) * NT + t];
        const float ii = xin[(size_t)NXY * NXY * NT + (size_t)(x * NXY + y) * NT + t];
        const float sr = csmap[(size_t)c * 2 * NXY * NXY + x * NXY + y];
        const float si = csmap[(size_t)c * 2 * NXY * NXY + NXY * NXY + x * NXY + y];
        srcB[((size_t)(t * NC + c) << 14) + ch * 2048 + mf * 256 + r * 16 + xl] =
            pack2h(sr * ir - si * ii, sr * ii + si * ir);
    }
}

// ---------------------------------------------------------------------------
// fwd_gemm: block = (t, c, kt of 64 kpoints), 256 thr, 4 waves.  (v12 body)
// Wave ws owns kp slice [kt*64 + ws*16, +16) and ALL 8 mf rows. 1 B-load per
// chunk per wave, in-wave epilogue, B-side complex rotation. (256,4) cap.
// ---------------------------------------------------------------------------
__global__ __launch_bounds__(256, 4) void fwd_gemm(const uint* __restrict__ ExC,
                                                   const uint* __restrict__ EyL,
                                                   const uint* __restrict__ srcB,
                                                   const float* __restrict__ dcomp,
                                                   float2* __restrict__ g) {
    const int t = blockIdx.x, c = blockIdx.y, kt = blockIdx.z;
    const int tid = threadIdx.x, lane = tid & 63, ws = tid >> 6;
    const int quad = lane >> 4, l15 = lane & 15;

    __shared__ __align__(16) _Float16 As[2][4096];

    f32x4 accr[8], acci[8];
#pragma unroll
    for (int mf = 0; mf < 8; ++mf) { accr[mf] = (f32x4)0.0f; acci[mf] = (f32x4)0.0f; }

    const uint* srcT = srcB + ((size_t)(t * NC + c) << 14);
    const uint* exB = ExC + (size_t)(t * 16 + (kt >> 1)) * 16384;
    const int kin0 = (kt & 1) * 64 + ws * 16;            // this wave's kp base (128-tile)

    // prologue: stage + B load for chunk 0
    F8 vA0 = *(const F8*)(srcT + tid * 8);
    F8 vA1 = *(const F8*)(srcT + tid * 8 + 4);
    F8 Bc = *(const F8*)(exB + (kin0 + l15) * 16 + quad * 4);

#pragma unroll 2
    for (int ch = 0; ch < 8; ++ch) {
        const int buf = ch & 1;
        *(F8*)&As[buf][tid * 16] = vA0;
        *(F8*)&As[buf][tid * 16 + 8] = vA1;
        __syncthreads();
        const int chn = ch < 7 ? ch + 1 : 7;
        vA0 = *(const F8*)(srcT + chn * 2048 + tid * 8);
        vA1 = *(const F8*)(srcT + chn * 2048 + tid * 8 + 4);
        F8 Bn = *(const F8*)(exB + chn * 2048 + (kin0 + l15) * 16 + quad * 4);
        __builtin_amdgcn_sched_barrier(0);
        // B-side rotation: Br = (bR,-bI) for real part, Bi = (bI,bR) for imag
        F8 Br, Bi;
#pragma unroll
        for (int d = 0; d < 4; ++d) {
            Br.u[d] = Bc.u[d] ^ 0x80000000u;
            Bi.u[d] = rot16(Bc.u[d]);
        }
#pragma unroll
        for (int mf = 0; mf < 8; ++mf) {
            F8 Ap = *(const F8*)&As[buf][mf * 512 + l15 * 32 + quad * 8];
            accr[mf] = MFMA16(Ap.h, Br.h, accr[mf]);
            acci[mf] = MFMA16(Ap.h, Bi.h, acci[mf]);
        }
        Bc = Bn;
    }

    // epilogue: in-wave y-reduction with EyL (all 8 mf), quad-reduce, store g
    const int kpoint = kt * 64 + ws * 16 + l15;
    const uint* eyRow = EyL + ((size_t)t * NK + kpoint) * NXY;
    float kdr = 0.f, kdi = 0.f;
#pragma unroll
    for (int mf = 0; mf < 8; ++mf) {
        F8 e4 = *(const F8*)(eyRow + mf * 16 + quad * 4);
#pragma unroll
        for (int rr = 0; rr < 4; ++rr) {
            float2 ey = unpack2h(e4.u[rr]);
            float cr = accr[mf][rr], ci = acci[mf][rr];
            kdr += ey.x * cr - ey.y * ci;
            kdi += ey.x * ci + ey.y * cr;
        }
    }
    kdr += __shfl_xor(kdr, 16); kdr += __shfl_xor(kdr, 32);
    kdi += __shfl_xor(kdi, 16); kdi += __shfl_xor(kdi, 32);
    if (lane < 16) {
        float w = dcomp[(size_t)kpoint * NT + t] * (1.0f / 16384.0f);
        g[((size_t)t * NK + kpoint) * NC + c] = make_float2(kdr * w, kdi * w);
    }
}

// ---------------------------------------------------------------------------
// adj_gemm: block = (t, ytile of 8 y, kz of 2 k-halves), 512 thr (8 waves).
// Each block: K' = 2048 halves (1024 kpoints), 32 chunks of 32 kpoints.
// Disjoint reads, private f32 partials. v19 issue order: B loads FIRST
// (consumed first), then build loads, then sched_barrier(0); MFMA phase
// starts at vmcnt(8) and build latency hides under it. Per-element scalar
// addressing kept (float4 variants re-sink the pipeline).
// ---------------------------------------------------------------------------
__global__ __launch_bounds__(512) void adj_gemm(const uint* __restrict__ ExT,
                                                const uint* __restrict__ EyL,
                                                const float2* __restrict__ g,
                                                const float* __restrict__ csmap,
                                                float* __restrict__ part) {
    const int t = blockIdx.x, yt = blockIdx.y, kz = blockIdx.z, ybase = yt * 8;
    const int tid = threadIdx.x, lane = tid & 63, ws = tid >> 6;
    const int quad = lane >> 4, l15 = lane & 15;
    const int x = ws * 16 + l15;
    const int kbase = kz * 1024;

    __shared__ __align__(16) _Float16 Ts[2][64][72];    // 64 K'-halves + 8 pad

    f32x4 accr[4], acci[4];
#pragma unroll
    for (int mf = 0; mf < 4; ++mf) { accr[mf] = (f32x4)0.0f; acci[mf] = (f32x4)0.0f; }

    const float2* gBase = g + (size_t)t * NK * NC;
    const uint* eyBase = EyL + (size_t)t * NK * NXY;
    const uint* exRow = ExT + (size_t)t * NXY * NK + (size_t)x * NK + kbase;

    const int bm = tid & 63;                 // build: row m
    const int bk4 = (tid >> 6) * 4;          // build: kpoint offset (0..28)
    const int by = ybase + (bm >> 3), bc = bm & 7;

    // build chunk 0
    {
        F8 w;
#pragma unroll
        for (int j = 0; j < 4; ++j) {
            int kp = kbase + bk4 + j;
            float2 gv = gBase[kp * NC + bc];
            float2 ey = unpack2h(eyBase[(size_t)kp * NXY + by]);
            w.u[j] = pack2h(ey.x * gv.x + ey.y * gv.y, ey.x * gv.y - ey.y * gv.x);
        }
        *(F8*)&Ts[0][bm][bk4 * 2] = w;
    }
    __syncthreads();

    for (int ch = 0; ch < 32; ++ch) {
        const int buf = ch & 1;
        const int chn = ch < 31 ? ch + 1 : 31;       // clamped: last iter redundant
        // --- B loads FIRST (consumed first by the rotation) ---
        F8 Bf0 = *(const F8*)(exRow + ch * 32 + quad * 4);
        F8 Bf1 = *(const F8*)(exRow + ch * 32 + 16 + quad * 4);
        // --- then build loads for chunk ch+1 (consumed after MFMA phase) ---
        const int kb = kbase + chn * 32 + bk4;
        float2 gv0 = gBase[(kb + 0) * NC + bc];
        float2 gv1 = gBase[(kb + 1) * NC + bc];
        float2 gv2 = gBase[(kb + 2) * NC + bc];
        float2 gv3 = gBase[(kb + 3) * NC + bc];
        uint ev0 = eyBase[(size_t)(kb + 0) * NXY + by];
        uint ev1 = eyBase[(size_t)(kb + 1) * NXY + by];
        uint ev2 = eyBase[(size_t)(kb + 2) * NXY + by];
        uint ev3 = eyBase[(size_t)(kb + 3) * NXY + by];
        __builtin_amdgcn_sched_barrier(0);
        // B-side rotation for imag accumulator: Bi = (-bI, bR)
        F8 Bi0, Bi1;
#pragma unroll
        for (int d = 0; d < 4; ++d) {
            Bi0.u[d] = rot16(Bf0.u[d]) ^ 0x00008000u;
            Bi1.u[d] = rot16(Bf1.u[d]) ^ 0x00008000u;
        }
        // --- MFMA phase on Ts[buf] ---
#pragma unroll
        for (int mf = 0; mf < 4; ++mf) {
            F8 Ap0 = *(const F8*)&Ts[buf][mf * 16 + l15][quad * 8];
            accr[mf] = MFMA16(Ap0.h, Bf0.h, accr[mf]);
            acci[mf] = MFMA16(Ap0.h, Bi0.h, acci[mf]);
            F8 Ap1 = *(const F8*)&Ts[buf][mf * 16 + l15][32 + quad * 8];
            accr[mf] = MFMA16(Ap1.h, Bf1.h, accr[mf]);
            acci[mf] = MFMA16(Ap1.h, Bi1.h, acci[mf]);
        }
        // --- pack + write build for chunk ch+1 ---
        {
            F8 w; float2 e;
            e = unpack2h(ev0); w.u[0] = pack2h(e.x*gv0.x + e.y*gv0.y, e.x*gv0.y - e.y*gv0.x);
            e = unpack2h(ev1); w.u[1] = pack2h(e.x*gv1.x + e.y*gv1.y, e.x*gv1.y - e.y*gv1.x);
            e = unpack2h(ev2); w.u[2] = pack2h(e.x*gv2.x + e.y*gv2.y, e.x*gv2.y - e.y*gv2.x);
            e = unpack2h(ev3); w.u[3] = pack2h(e.x*gv3.x + e.y*gv3.y, e.x*gv3.y - e.y*gv3.x);
            *(F8*)&Ts[buf ^ 1][bm][bk4 * 2] = w;
        }
        __syncthreads();
    }

    // epilogue: coil-combine with conj(smap), write partial [kz][2][x][y][t]
    float* po = part + (size_t)kz * 2 * NXY * NXY * NT;
#pragma unroll
    for (int mf = 0; mf < 4; ++mf) {
        const int y = ybase + 2 * mf + (quad >> 1);
        float or_ = 0.f, oi_ = 0.f;
#pragma unroll
        for (int r = 0; r < 4; ++r) {
            int c = 4 * (quad & 1) + r;
            float sr = csmap[(size_t)c * 2 * NXY * NXY + x * NXY + y];
            float si = csmap[(size_t)c * 2 * NXY * NXY + NXY * NXY + x * NXY + y];
            float xr = accr[mf][r], xi = acci[mf][r];
            or_ += sr * xr + si * xi;
            oi_ += sr * xi - si * xr;
        }
        or_ += __shfl_xor(or_, 16);
        oi_ += __shfl_xor(oi_, 16);
        if ((lane & 16) == 0) {
            po[(size_t)(x * NXY + y) * NT + t] = or_;
            po[(size_t)NXY * NXY * NT + (size_t)(x * NXY + y) * NT + t] = oi_;
        }
    }
}

// ---------------------------------------------------------------------------
// combine: out = part0 + part1 (elementwise over 2*128*128*16 floats)
// ---------------------------------------------------------------------------
__global__ __launch_bounds__(256) void combine(const float* __restrict__ part,
                                               float* __restrict__ out) {
    const int idx = blockIdx.x * 256 + threadIdx.x;      // < 524288
    out[idx] = part[idx] + part[idx + 2 * NXY * NXY * NT];
}

// ---------------------------------------------------------------------------
extern "C" void kernel_launch(void* const* d_in, const int* in_sizes, int n_in,
                              void* d_out, int out_size, void* d_ws, size_t ws_size,
                              hipStream_t stream) {
    const float* xin   = (const float*)d_in[0];  // (2,128,128,16)
    const float* ktraj = (const float*)d_in[1];  // (2,2048,16)
    const float* csmap = (const float*)d_in[2];  // (8,2,128,128)
    const float* dcomp = (const float*)d_in[3];  // (2048,16)
    float* out = (float*)d_out;                  // (2,128,128,16)

    // ws layout: ExC + ExT + EyL (16MB each) + srcB 8MB + g 2MB + part 4MB = 62MB
    const size_t TBL = (size_t)NT * NK * NXY;            // 4.19M dwords per table
    uint* ExC  = (uint*)d_ws;                            // [t][kt][xc][kp][xq]
    uint* ExT  = ExC + TBL;                              // [t][x][k]
    uint* EyL  = ExT + TBL;                              // [t][k][y]
    uint* srcB = EyL + TBL;                              // fragment-ordered
    float2* g  = (float2*)(srcB + (size_t)NT * NC * NXY * NXY);  // [t][k][c]
    float* part = (float*)(g + (size_t)NT * NK * NC);    // [kz2][2][x][y][t]

    prep_all<<<dim3(40960), 256, 0, stream>>>(ktraj, xin, csmap, ExC, ExT, EyL, srcB);
    fwd_gemm<<<dim3(NT, NC, 32), 256, 0, stream>>>(ExC, EyL, srcB, dcomp, g);
    adj_gemm<<<dim3(NT, NXY / 8, 2), 512, 0, stream>>>(ExT, EyL, g, csmap, part);
    combine<<<dim3(2048), 256, 0, stream>>>(part, out);
}

// Round 19
// 204.026 us; speedup vs baseline: 1.0984x; 1.0358x over previous
//
#include <hip/hip_runtime.h>

// Frame-wise E^H D E exact NDFT via separable phasors as two complex GEMMs on
// fp16 matrix cores (fp32 accumulate).
// v20 = v19 (211.3us best) + ONE isolated change: adj B-fragment layout.
//  - ExB[t][kg512][x128][kq4] replaces ExT[t][x][k] as adj's B source: a
//    lane's F8 fragment = 4 consecutive dwords; a wave-load = 4x256B runs
//    (8 trans) instead of 64 lanes at 8KB stride (64 trans). Cuts adj's
//    B-transaction pool 8x (~65k cy/CU -> ~8k). This was v5's idea but v5
//    bundled it with the tiled-Ey build addressing (v11-convicted re-sink)
//    and csmapT; here it is isolated on the v19 base (build untouched,
//    addressing linear-in-ch so no sinking trigger).
//  - adj build / kz=2 split / fwd (256,4) / preps otherwise v19 VERBATIM.

#define NT 16
#define NK 2048
#define NXY 128
#define NC 8

typedef _Float16 f16x8 __attribute__((ext_vector_type(8)));
typedef float f32x4 __attribute__((ext_vector_type(4)));

union F8 { f16x8 h; uint u[4]; };

#define MFMA16(a, b, c) __builtin_amdgcn_mfma_f32_16x16x32_f16((a), (b), (c), 0, 0, 0)

__device__ __forceinline__ uint pack2h(float a, float b) {
    union { _Float16 h[2]; uint u; } p;
    p.h[0] = (_Float16)a; p.h[1] = (_Float16)b;
    return p.u;
}
__device__ __forceinline__ float2 unpack2h(uint v) {
    union { uint u; _Float16 h[2]; } p;
    p.u = v;
    return make_float2((float)p.h[0], (float)p.h[1]);
}
__device__ __forceinline__ uint rot16(uint v) { return (v >> 16) | (v << 16); }

// ---------------------------------------------------------------------------
// prep_all: fused preps, branch on block range (block-uniform divergence).
//  [0, 16384):      phasA -> tiled ExC [t][kt16][xc8][kp128][xq16] + linear
//                   EyL [t][k][y]
//  [16384, 32768):  phasB -> ExB [t][kg512][x128][kq4] (adj B fragments)
//  [32768, 40960):  src   -> srcB fragment order [t][c][ch8][mf8][r16][xl16]
// ---------------------------------------------------------------------------
__global__ __launch_bounds__(256) void prep_all(const float* __restrict__ ktraj,
                                                const float* __restrict__ xin,
                                                const float* __restrict__ csmap,
                                                uint* __restrict__ ExC,
                                                uint* __restrict__ ExB,
                                                uint* __restrict__ EyL,
                                                uint* __restrict__ srcB) {
    const int b = blockIdx.x;
    const int tid = threadIdx.x;
    if (b < 16384) {
        // ---- phasA ----
        const int t = b >> 10;
        const int k = (b & 1023) * 2 + (tid >> 7);
        const int x = tid & 127;
        const float kx = ktraj[(size_t)k * NT + t];
        const float ky = ktraj[(size_t)(NK + k) * NT + t];
        const float xm = (float)(x - 64);
        float s, c;
        __sincosf(-kx * xm, &s, &c);
        ExC[((size_t)(t * 16 + (k >> 7)) * 8 + (x >> 4)) * 2048 +
            (size_t)(k & 127) * 16 + (x & 15)] = pack2h(c, s);
        __sincosf(-ky * xm, &s, &c);
        EyL[((size_t)t * NK + k) * NXY + x] = pack2h(c, s);
    } else if (b < 32768) {
        // ---- phasB: ExB[t][kg][x][kq], idx linear = output linear ----
        const int idx = (b - 16384) * 256 + tid;     // < 16*512*128*4 = 4.19M
        const int kq = idx & 3, x = (idx >> 2) & 127, kg = (idx >> 9) & 511,
                  t = idx >> 18;
        const int kp = kg * 4 + kq;
        const float kx = ktraj[(size_t)kp * NT + t];
        float s, c;
        __sincosf(-kx * (float)(x - 64), &s, &c);
        ExB[idx] = pack2h(c, s);
    } else {
        // ---- src ----
        const int idx = (b - 32768) * 256 + tid;   // < 2^21
        const int t = idx & 15, r = (idx >> 4) & 15, xl = (idx >> 8) & 15,
                  mf = (idx >> 12) & 7, ch = (idx >> 15) & 7, c = idx >> 18;
        const int x = ch * 16 + xl, y = mf * 16 + r;
        const float ir = xin[(size_t)(x * NXY + y) * NT + t];
        const float ii = xin[(size_t)NXY * NXY * NT + (size_t)(x * NXY + y) * NT + t];
        const float sr = csmap[(size_t)c * 2 * NXY * NXY + x * NXY + y];
        const float si = csmap[(size_t)c * 2 * NXY * NXY + NXY * NXY + x * NXY + y];
        srcB[((size_t)(t * NC + c) << 14) + ch * 2048 + mf * 256 + r * 16 + xl] =
            pack2h(sr * ir - si * ii, sr * ii + si * ir);
    }
}

// ---------------------------------------------------------------------------
// fwd_gemm: block = (t, c, kt of 64 kpoints), 256 thr, 4 waves.  (v19 verbatim)
// Wave ws owns kp slice [kt*64 + ws*16, +16) and ALL 8 mf rows. 1 B-load per
// chunk per wave, in-wave epilogue, B-side complex rotation. (256,4) cap.
// ---------------------------------------------------------------------------
__global__ __launch_bounds__(256, 4) void fwd_gemm(const uint* __restrict__ ExC,
                                                   const uint* __restrict__ EyL,
                                                   const uint* __restrict__ srcB,
                                                   const float* __restrict__ dcomp,
                                                   float2* __restrict__ g) {
    const int t = blockIdx.x, c = blockIdx.y, kt = blockIdx.z;
    const int tid = threadIdx.x, lane = tid & 63, ws = tid >> 6;
    const int quad = lane >> 4, l15 = lane & 15;

    __shared__ __align__(16) _Float16 As[2][4096];

    f32x4 accr[8], acci[8];
#pragma unroll
    for (int mf = 0; mf < 8; ++mf) { accr[mf] = (f32x4)0.0f; acci[mf] = (f32x4)0.0f; }

    const uint* srcT = srcB + ((size_t)(t * NC + c) << 14);
    const uint* exB = ExC + (size_t)(t * 16 + (kt >> 1)) * 16384;
    const int kin0 = (kt & 1) * 64 + ws * 16;            // this wave's kp base (128-tile)

    // prologue: stage + B load for chunk 0
    F8 vA0 = *(const F8*)(srcT + tid * 8);
    F8 vA1 = *(const F8*)(srcT + tid * 8 + 4);
    F8 Bc = *(const F8*)(exB + (kin0 + l15) * 16 + quad * 4);

#pragma unroll 2
    for (int ch = 0; ch < 8; ++ch) {
        const int buf = ch & 1;
        *(F8*)&As[buf][tid * 16] = vA0;
        *(F8*)&As[buf][tid * 16 + 8] = vA1;
        __syncthreads();
        const int chn = ch < 7 ? ch + 1 : 7;
        vA0 = *(const F8*)(srcT + chn * 2048 + tid * 8);
        vA1 = *(const F8*)(srcT + chn * 2048 + tid * 8 + 4);
        F8 Bn = *(const F8*)(exB + chn * 2048 + (kin0 + l15) * 16 + quad * 4);
        __builtin_amdgcn_sched_barrier(0);
        // B-side rotation: Br = (bR,-bI) for real part, Bi = (bI,bR) for imag
        F8 Br, Bi;
#pragma unroll
        for (int d = 0; d < 4; ++d) {
            Br.u[d] = Bc.u[d] ^ 0x80000000u;
            Bi.u[d] = rot16(Bc.u[d]);
        }
#pragma unroll
        for (int mf = 0; mf < 8; ++mf) {
            F8 Ap = *(const F8*)&As[buf][mf * 512 + l15 * 32 + quad * 8];
            accr[mf] = MFMA16(Ap.h, Br.h, accr[mf]);
            acci[mf] = MFMA16(Ap.h, Bi.h, acci[mf]);
        }
        Bc = Bn;
    }

    // epilogue: in-wave y-reduction with EyL (all 8 mf), quad-reduce, store g
    const int kpoint = kt * 64 + ws * 16 + l15;
    const uint* eyRow = EyL + ((size_t)t * NK + kpoint) * NXY;
    float kdr = 0.f, kdi = 0.f;
#pragma unroll
    for (int mf = 0; mf < 8; ++mf) {
        F8 e4 = *(const F8*)(eyRow + mf * 16 + quad * 4);
#pragma unroll
        for (int rr = 0; rr < 4; ++rr) {
            float2 ey = unpack2h(e4.u[rr]);
            float cr = accr[mf][rr], ci = acci[mf][rr];
            kdr += ey.x * cr - ey.y * ci;
            kdi += ey.x * ci + ey.y * cr;
        }
    }
    kdr += __shfl_xor(kdr, 16); kdr += __shfl_xor(kdr, 32);
    kdi += __shfl_xor(kdi, 16); kdi += __shfl_xor(kdi, 32);
    if (lane < 16) {
        float w = dcomp[(size_t)kpoint * NT + t] * (1.0f / 16384.0f);
        g[((size_t)t * NK + kpoint) * NC + c] = make_float2(kdr * w, kdi * w);
    }
}

// ---------------------------------------------------------------------------
// adj_gemm: block = (t, ytile of 8 y, kz of 2 k-halves), 512 thr (8 waves).
// Each block: K' = 2048 halves (1024 kpoints), 32 chunks of 32 kpoints.
// Disjoint reads, private f32 partials. v19 body; ONLY the B loads changed:
// fragment-contiguous ExB[t][kg][x][kq] -> wave-load = 4x256B runs (8 trans
// vs 64). B loads first, build loads, sched_barrier(0), MFMA, pack, barrier.
// ---------------------------------------------------------------------------
__global__ __launch_bounds__(512) void adj_gemm(const uint* __restrict__ ExB,
                                                const uint* __restrict__ EyL,
                                                const float2* __restrict__ g,
                                                const float* __restrict__ csmap,
                                                float* __restrict__ part) {
    const int t = blockIdx.x, yt = blockIdx.y, kz = blockIdx.z, ybase = yt * 8;
    const int tid = threadIdx.x, lane = tid & 63, ws = tid >> 6;
    const int quad = lane >> 4, l15 = lane & 15;
    const int x = ws * 16 + l15;
    const int kbase = kz * 1024;

    __shared__ __align__(16) _Float16 Ts[2][64][72];    // 64 K'-halves + 8 pad

    f32x4 accr[4], acci[4];
#pragma unroll
    for (int mf = 0; mf < 4; ++mf) { accr[mf] = (f32x4)0.0f; acci[mf] = (f32x4)0.0f; }

    const float2* gBase = g + (size_t)t * NK * NC;
    const uint* eyBase = EyL + (size_t)t * NK * NXY;
    // ExB fragment base for this lane: row (kg, x) -> 4 dwords.
    // kg for chunk ch, slot ks: kbase/4 + ch*8 + ks*4 + quad.
    const uint* exFrag = ExB + (size_t)t * 262144 +
                         ((size_t)(kbase >> 2) + quad) * 512 + (size_t)x * 4;

    const int bm = tid & 63;                 // build: row m
    const int bk4 = (tid >> 6) * 4;          // build: kpoint offset (0..28)
    const int by = ybase + (bm >> 3), bc = bm & 7;

    // build chunk 0
    {
        F8 w;
#pragma unroll
        for (int j = 0; j < 4; ++j) {
            int kp = kbase + bk4 + j;
            float2 gv = gBase[kp * NC + bc];
            float2 ey = unpack2h(eyBase[(size_t)kp * NXY + by]);
            w.u[j] = pack2h(ey.x * gv.x + ey.y * gv.y, ey.x * gv.y - ey.y * gv.x);
        }
        *(F8*)&Ts[0][bm][bk4 * 2] = w;
    }
    __syncthreads();

    for (int ch = 0; ch < 32; ++ch) {
        const int buf = ch & 1;
        const int chn = ch < 31 ? ch + 1 : 31;       // clamped: last iter redundant
        // --- B loads FIRST (fragment-contiguous; consumed first) ---
        F8 Bf0 = *(const F8*)(exFrag + (size_t)ch * 4096);
        F8 Bf1 = *(const F8*)(exFrag + (size_t)ch * 4096 + 2048);
        // --- then build loads for chunk ch+1 (consumed after MFMA phase) ---
        const int kb = kbase + chn * 32 + bk4;
        float2 gv0 = gBase[(kb + 0) * NC + bc];
        float2 gv1 = gBase[(kb + 1) * NC + bc];
        float2 gv2 = gBase[(kb + 2) * NC + bc];
        float2 gv3 = gBase[(kb + 3) * NC + bc];
        uint ev0 = eyBase[(size_t)(kb + 0) * NXY + by];
        uint ev1 = eyBase[(size_t)(kb + 1) * NXY + by];
        uint ev2 = eyBase[(size_t)(kb + 2) * NXY + by];
        uint ev3 = eyBase[(size_t)(kb + 3) * NXY + by];
        __builtin_amdgcn_sched_barrier(0);
        // B-side rotation for imag accumulator: Bi = (-bI, bR)
        F8 Bi0, Bi1;
#pragma unroll
        for (int d = 0; d < 4; ++d) {
            Bi0.u[d] = rot16(Bf0.u[d]) ^ 0x00008000u;
            Bi1.u[d] = rot16(Bf1.u[d]) ^ 0x00008000u;
        }
        // --- MFMA phase on Ts[buf] ---
#pragma unroll
        for (int mf = 0; mf < 4; ++mf) {
            F8 Ap0 = *(const F8*)&Ts[buf][mf * 16 + l15][quad * 8];
            accr[mf] = MFMA16(Ap0.h, Bf0.h, accr[mf]);
            acci[mf] = MFMA16(Ap0.h, Bi0.h, acci[mf]);
            F8 Ap1 = *(const F8*)&Ts[buf][mf * 16 + l15][32 + quad * 8];
            accr[mf] = MFMA16(Ap1.h, Bf1.h, accr[mf]);
            acci[mf] = MFMA16(Ap1.h, Bi1.h, acci[mf]);
        }
        // --- pack + write build for chunk ch+1 ---
        {
            F8 w; float2 e;
            e = unpack2h(ev0); w.u[0] = pack2h(e.x*gv0.x + e.y*gv0.y, e.x*gv0.y - e.y*gv0.x);
            e = unpack2h(ev1); w.u[1] = pack2h(e.x*gv1.x + e.y*gv1.y, e.x*gv1.y - e.y*gv1.x);
            e = unpack2h(ev2); w.u[2] = pack2h(e.x*gv2.x + e.y*gv2.y, e.x*gv2.y - e.y*gv2.x);
            e = unpack2h(ev3); w.u[3] = pack2h(e.x*gv3.x + e.y*gv3.y, e.x*gv3.y - e.y*gv3.x);
            *(F8*)&Ts[buf ^ 1][bm][bk4 * 2] = w;
        }
        __syncthreads();
    }

    // epilogue: coil-combine with conj(smap), write partial [kz][2][x][y][t]
    float* po = part + (size_t)kz * 2 * NXY * NXY * NT;
#pragma unroll
    for (int mf = 0; mf < 4; ++mf) {
        const int y = ybase + 2 * mf + (quad >> 1);
        float or_ = 0.f, oi_ = 0.f;
#pragma unroll
        for (int r = 0; r < 4; ++r) {
            int c = 4 * (quad & 1) + r;
            float sr = csmap[(size_t)c * 2 * NXY * NXY + x * NXY + y];
            float si = csmap[(size_t)c * 2 * NXY * NXY + NXY * NXY + x * NXY + y];
            float xr = accr[mf][r], xi = acci[mf][r];
            or_ += sr * xr + si * xi;
            oi_ += sr * xi - si * xr;
        }
        or_ += __shfl_xor(or_, 16);
        oi_ += __shfl_xor(oi_, 16);
        if ((lane & 16) == 0) {
            po[(size_t)(x * NXY + y) * NT + t] = or_;
            po[(size_t)NXY * NXY * NT + (size_t)(x * NXY + y) * NT + t] = oi_;
        }
    }
}

// ---------------------------------------------------------------------------
// combine: out = part0 + part1 (elementwise over 2*128*128*16 floats)
// ---------------------------------------------------------------------------
__global__ __launch_bounds__(256) void combine(const float* __restrict__ part,
                                               float* __restrict__ out) {
    const int idx = blockIdx.x * 256 + threadIdx.x;      // < 524288
    out[idx] = part[idx] + part[idx + 2 * NXY * NXY * NT];
}

// ---------------------------------------------------------------------------
extern "C" void kernel_launch(void* const* d_in, const int* in_sizes, int n_in,
                              void* d_out, int out_size, void* d_ws, size_t ws_size,
                              hipStream_t stream) {
    const float* xin   = (const float*)d_in[0];  // (2,128,128,16)
    const float* ktraj = (const float*)d_in[1];  // (2,2048,16)
    const float* csmap = (const float*)d_in[2];  // (8,2,128,128)
    const float* dcomp = (const float*)d_in[3];  // (2048,16)
    float* out = (float*)d_out;                  // (2,128,128,16)

    // ws layout: ExC + ExB + EyL (16MB each) + srcB 8MB + g 2MB + part 4MB = 62MB
    const size_t TBL = (size_t)NT * NK * NXY;            // 4.19M dwords per table
    uint* ExC  = (uint*)d_ws;                            // [t][kt][xc][kp][xq]
    uint* ExB  = ExC + TBL;                              // [t][kg][x][kq]
    uint* EyL  = ExB + TBL;                              // [t][k][y]
    uint* srcB = EyL + TBL;                              // fragment-ordered
    float2* g  = (float2*)(srcB + (size_t)NT * NC * NXY * NXY);  // [t][k][c]
    float* part = (float*)(g + (size_t)NT * NK * NC);    // [kz2][2][x][y][t]

    prep_all<<<dim3(40960), 256, 0, stream>>>(ktraj, xin, csmap, ExC, ExB, EyL, srcB);
    fwd_gemm<<<dim3(NT, NC, 32), 256, 0, stream>>>(ExC, EyL, srcB, dcomp, g);
    adj_gemm<<<dim3(NT, NXY / 8, 2), 512, 0, stream>>>(ExB, EyL, g, csmap, part);
    combine<<<dim3(2048), 256, 0, stream>>>(part, out);
}

// Round 20
// 200.334 us; speedup vs baseline: 1.1186x; 1.0184x over previous
//
#include <hip/hip_runtime.h>

// Frame-wise E^H D E exact NDFT via separable phasors as two complex GEMMs on
// fp16 matrix cores (fp32 accumulate).
// v21 = v20 (204.0us best) + ONE isolated change: Ey re-keyed [t][y][k] (EyT).
//  - adj build Ey loads: 4 consecutive k per thread = one 16B run per by-row;
//    wave pool 32 -> 8 transactions/chunk (the largest remaining pool after
//    v20 cut B 64 -> 8). Row base (by*2048) is a per-thread constant.
//  - fwd epilogue reads EyT as 32 scalar dwords (same transaction count by
//    arithmetic: 128/wave either way; epilogue-only issue cost).
//  - prep_all: Ey generation moved to its own k-contiguous branch (same
//    sincos count, same write bytes). ws stays 62MB.
//  - adj kz=2 split / build order / fwd (256,4) / ExB: v20 VERBATIM.

#define NT 16
#define NK 2048
#define NXY 128
#define NC 8

typedef _Float16 f16x8 __attribute__((ext_vector_type(8)));
typedef float f32x4 __attribute__((ext_vector_type(4)));

union F8 { f16x8 h; uint u[4]; };

#define MFMA16(a, b, c) __builtin_amdgcn_mfma_f32_16x16x32_f16((a), (b), (c), 0, 0, 0)

__device__ __forceinline__ uint pack2h(float a, float b) {
    union { _Float16 h[2]; uint u; } p;
    p.h[0] = (_Float16)a; p.h[1] = (_Float16)b;
    return p.u;
}
__device__ __forceinline__ float2 unpack2h(uint v) {
    union { uint u; _Float16 h[2]; } p;
    p.u = v;
    return make_float2((float)p.h[0], (float)p.h[1]);
}
__device__ __forceinline__ uint rot16(uint v) { return (v >> 16) | (v << 16); }

// ---------------------------------------------------------------------------
// prep_all: fused preps, branch on block range (block-uniform divergence).
//  [0, 16384):      phasA -> tiled ExC [t][kt16][xc8][kp128][xq16]
//  [16384, 32768):  phasB -> ExB [t][kg512][x128][kq4] (adj B fragments)
//  [32768, 49152):  phasC -> EyT [t][y128][k2048]
//  [49152, 57344):  src   -> srcB fragment order [t][c][ch8][mf8][r16][xl16]
// ---------------------------------------------------------------------------
__global__ __launch_bounds__(256) void prep_all(const float* __restrict__ ktraj,
                                                const float* __restrict__ xin,
                                                const float* __restrict__ csmap,
                                                uint* __restrict__ ExC,
                                                uint* __restrict__ ExB,
                                                uint* __restrict__ EyT,
                                                uint* __restrict__ srcB) {
    const int b = blockIdx.x;
    const int tid = threadIdx.x;
    if (b < 16384) {
        // ---- phasA: ExC ----
        const int t = b >> 10;
        const int k = (b & 1023) * 2 + (tid >> 7);
        const int x = tid & 127;
        const float kx = ktraj[(size_t)k * NT + t];
        float s, c;
        __sincosf(-kx * (float)(x - 64), &s, &c);
        ExC[((size_t)(t * 16 + (k >> 7)) * 8 + (x >> 4)) * 2048 +
            (size_t)(k & 127) * 16 + (x & 15)] = pack2h(c, s);
    } else if (b < 32768) {
        // ---- phasB: ExB[t][kg][x][kq], idx linear = output linear ----
        const int idx = (b - 16384) * 256 + tid;     // < 4.19M
        const int kq = idx & 3, x = (idx >> 2) & 127, kg = (idx >> 9) & 511,
                  t = idx >> 18;
        const int kp = kg * 4 + kq;
        const float kx = ktraj[(size_t)kp * NT + t];
        float s, c;
        __sincosf(-kx * (float)(x - 64), &s, &c);
        ExB[idx] = pack2h(c, s);
    } else if (b < 49152) {
        // ---- phasC: EyT[t][y][k], idx linear = output linear ----
        const int idx = (b - 32768) * 256 + tid;     // < 4.19M
        const int k = idx & 2047, y = (idx >> 11) & 127, t = idx >> 18;
        const float ky = ktraj[(size_t)(NK + k) * NT + t];
        float s, c;
        __sincosf(-ky * (float)(y - 64), &s, &c);
        EyT[idx] = pack2h(c, s);
    } else {
        // ---- src ----
        const int idx = (b - 49152) * 256 + tid;   // < 2^21
        const int t = idx & 15, r = (idx >> 4) & 15, xl = (idx >> 8) & 15,
                  mf = (idx >> 12) & 7, ch = (idx >> 15) & 7, c = idx >> 18;
        const int x = ch * 16 + xl, y = mf * 16 + r;
        const float ir = xin[(size_t)(x * NXY + y) * NT + t];
        const float ii = xin[(size_t)NXY * NXY * NT + (size_t)(x * NXY + y) * NT + t];
        const float sr = csmap[(size_t)c * 2 * NXY * NXY + x * NXY + y];
        const float si = csmap[(size_t)c * 2 * NXY * NXY + NXY * NXY + x * NXY + y];
        srcB[((size_t)(t * NC + c) << 14) + ch * 2048 + mf * 256 + r * 16 + xl] =
            pack2h(sr * ir - si * ii, sr * ii + si * ir);
    }
}

// ---------------------------------------------------------------------------
// fwd_gemm: block = (t, c, kt of 64 kpoints), 256 thr, 4 waves.  (v20 body)
// Wave ws owns kp slice [kt*64 + ws*16, +16) and ALL 8 mf rows. 1 B-load per
// chunk per wave, B-side complex rotation. Epilogue reads EyT[t][y][k] as
// scalar dwords (same transaction count as the old EyL F8 reads).
// ---------------------------------------------------------------------------
__global__ __launch_bounds__(256, 4) void fwd_gemm(const uint* __restrict__ ExC,
                                                   const uint* __restrict__ EyT,
                                                   const uint* __restrict__ srcB,
                                                   const float* __restrict__ dcomp,
                                                   float2* __restrict__ g) {
    const int t = blockIdx.x, c = blockIdx.y, kt = blockIdx.z;
    const int tid = threadIdx.x, lane = tid & 63, ws = tid >> 6;
    const int quad = lane >> 4, l15 = lane & 15;

    __shared__ __align__(16) _Float16 As[2][4096];

    f32x4 accr[8], acci[8];
#pragma unroll
    for (int mf = 0; mf < 8; ++mf) { accr[mf] = (f32x4)0.0f; acci[mf] = (f32x4)0.0f; }

    const uint* srcT = srcB + ((size_t)(t * NC + c) << 14);
    const uint* exB = ExC + (size_t)(t * 16 + (kt >> 1)) * 16384;
    const int kin0 = (kt & 1) * 64 + ws * 16;            // this wave's kp base (128-tile)

    // prologue: stage + B load for chunk 0
    F8 vA0 = *(const F8*)(srcT + tid * 8);
    F8 vA1 = *(const F8*)(srcT + tid * 8 + 4);
    F8 Bc = *(const F8*)(exB + (kin0 + l15) * 16 + quad * 4);

#pragma unroll 2
    for (int ch = 0; ch < 8; ++ch) {
        const int buf = ch & 1;
        *(F8*)&As[buf][tid * 16] = vA0;
        *(F8*)&As[buf][tid * 16 + 8] = vA1;
        __syncthreads();
        const int chn = ch < 7 ? ch + 1 : 7;
        vA0 = *(const F8*)(srcT + chn * 2048 + tid * 8);
        vA1 = *(const F8*)(srcT + chn * 2048 + tid * 8 + 4);
        F8 Bn = *(const F8*)(exB + chn * 2048 + (kin0 + l15) * 16 + quad * 4);
        __builtin_amdgcn_sched_barrier(0);
        // B-side rotation: Br = (bR,-bI) for real part, Bi = (bI,bR) for imag
        F8 Br, Bi;
#pragma unroll
        for (int d = 0; d < 4; ++d) {
            Br.u[d] = Bc.u[d] ^ 0x80000000u;
            Bi.u[d] = rot16(Bc.u[d]);
        }
#pragma unroll
        for (int mf = 0; mf < 8; ++mf) {
            F8 Ap = *(const F8*)&As[buf][mf * 512 + l15 * 32 + quad * 8];
            accr[mf] = MFMA16(Ap.h, Br.h, accr[mf]);
            acci[mf] = MFMA16(Ap.h, Bi.h, acci[mf]);
        }
        Bc = Bn;
    }

    // epilogue: in-wave y-reduction with EyT (scalar dword reads), quad-reduce
    const int kpoint = kt * 64 + ws * 16 + l15;
    const uint* eyK = EyT + (size_t)t * 262144 + kpoint;   // per-lane col base
    float kdr = 0.f, kdi = 0.f;
#pragma unroll
    for (int mf = 0; mf < 8; ++mf) {
#pragma unroll
        for (int rr = 0; rr < 4; ++rr) {
            const int y = mf * 16 + quad * 4 + rr;
            float2 ey = unpack2h(eyK[(size_t)y * 2048]);
            float cr = accr[mf][rr], ci = acci[mf][rr];
            kdr += ey.x * cr - ey.y * ci;
            kdi += ey.x * ci + ey.y * cr;
        }
    }
    kdr += __shfl_xor(kdr, 16); kdr += __shfl_xor(kdr, 32);
    kdi += __shfl_xor(kdi, 16); kdi += __shfl_xor(kdi, 32);
    if (lane < 16) {
        float w = dcomp[(size_t)kpoint * NT + t] * (1.0f / 16384.0f);
        g[((size_t)t * NK + kpoint) * NC + c] = make_float2(kdr * w, kdi * w);
    }
}

// ---------------------------------------------------------------------------
// adj_gemm: block = (t, ytile of 8 y, kz of 2 k-halves), 512 thr (8 waves).
// Each block: 32 chunks of 32 kpoints. Disjoint reads, private f32 partials.
// v20 body; ONLY the Ey build loads changed: EyT[t][y][k] -> 4 consecutive
// dwords per thread (one 16B run per by-row; wave pool 32 -> 8 trans).
// ---------------------------------------------------------------------------
__global__ __launch_bounds__(512) void adj_gemm(const uint* __restrict__ ExB,
                                                const uint* __restrict__ EyT,
                                                const float2* __restrict__ g,
                                                const float* __restrict__ csmap,
                                                float* __restrict__ part) {
    const int t = blockIdx.x, yt = blockIdx.y, kz = blockIdx.z, ybase = yt * 8;
    const int tid = threadIdx.x, lane = tid & 63, ws = tid >> 6;
    const int quad = lane >> 4, l15 = lane & 15;
    const int x = ws * 16 + l15;
    const int kbase = kz * 1024;

    __shared__ __align__(16) _Float16 Ts[2][64][72];    // 64 K'-halves + 8 pad

    f32x4 accr[4], acci[4];
#pragma unroll
    for (int mf = 0; mf < 4; ++mf) { accr[mf] = (f32x4)0.0f; acci[mf] = (f32x4)0.0f; }

    const float2* gBase = g + (size_t)t * NK * NC;
    // ExB fragment base for this lane: row (kg, x) -> 4 dwords.
    const uint* exFrag = ExB + (size_t)t * 262144 +
                         ((size_t)(kbase >> 2) + quad) * 512 + (size_t)x * 4;

    const int bm = tid & 63;                 // build: row m
    const int bk4 = (tid >> 6) * 4;          // build: kpoint offset (0..28)
    const int by = ybase + (bm >> 3), bc = bm & 7;
    const uint* eyRow = EyT + (size_t)t * 262144 + (size_t)by * 2048;  // per-thread row

    // build chunk 0
    {
        F8 w;
#pragma unroll
        for (int j = 0; j < 4; ++j) {
            int kp = kbase + bk4 + j;
            float2 gv = gBase[kp * NC + bc];
            float2 ey = unpack2h(eyRow[kp]);
            w.u[j] = pack2h(ey.x * gv.x + ey.y * gv.y, ey.x * gv.y - ey.y * gv.x);
        }
        *(F8*)&Ts[0][bm][bk4 * 2] = w;
    }
    __syncthreads();

    for (int ch = 0; ch < 32; ++ch) {
        const int buf = ch & 1;
        const int chn = ch < 31 ? ch + 1 : 31;       // clamped: last iter redundant
        // --- B loads FIRST (fragment-contiguous; consumed first) ---
        F8 Bf0 = *(const F8*)(exFrag + (size_t)ch * 4096);
        F8 Bf1 = *(const F8*)(exFrag + (size_t)ch * 4096 + 2048);
        // --- then build loads for chunk ch+1 (consumed after MFMA phase) ---
        const int kb = kbase + chn * 32 + bk4;
        float2 gv0 = gBase[(kb + 0) * NC + bc];
        float2 gv1 = gBase[(kb + 1) * NC + bc];
        float2 gv2 = gBase[(kb + 2) * NC + bc];
        float2 gv3 = gBase[(kb + 3) * NC + bc];
        uint ev0 = eyRow[kb + 0];
        uint ev1 = eyRow[kb + 1];
        uint ev2 = eyRow[kb + 2];
        uint ev3 = eyRow[kb + 3];
        __builtin_amdgcn_sched_barrier(0);
        // B-side rotation for imag accumulator: Bi = (-bI, bR)
        F8 Bi0, Bi1;
#pragma unroll
        for (int d = 0; d < 4; ++d) {
            Bi0.u[d] = rot16(Bf0.u[d]) ^ 0x00008000u;
            Bi1.u[d] = rot16(Bf1.u[d]) ^ 0x00008000u;
        }
        // --- MFMA phase on Ts[buf] ---
#pragma unroll
        for (int mf = 0; mf < 4; ++mf) {
            F8 Ap0 = *(const F8*)&Ts[buf][mf * 16 + l15][quad * 8];
            accr[mf] = MFMA16(Ap0.h, Bf0.h, accr[mf]);
            acci[mf] = MFMA16(Ap0.h, Bi0.h, acci[mf]);
            F8 Ap1 = *(const F8*)&Ts[buf][mf * 16 + l15][32 + quad * 8];
            accr[mf] = MFMA16(Ap1.h, Bf1.h, accr[mf]);
            acci[mf] = MFMA16(Ap1.h, Bi1.h, acci[mf]);
        }
        // --- pack + write build for chunk ch+1 ---
        {
            F8 w; float2 e;
            e = unpack2h(ev0); w.u[0] = pack2h(e.x*gv0.x + e.y*gv0.y, e.x*gv0.y - e.y*gv0.x);
            e = unpack2h(ev1); w.u[1] = pack2h(e.x*gv1.x + e.y*gv1.y, e.x*gv1.y - e.y*gv1.x);
            e = unpack2h(ev2); w.u[2] = pack2h(e.x*gv2.x + e.y*gv2.y, e.x*gv2.y - e.y*gv2.x);
            e = unpack2h(ev3); w.u[3] = pack2h(e.x*gv3.x + e.y*gv3.y, e.x*gv3.y - e.y*gv3.x);
            *(F8*)&Ts[buf ^ 1][bm][bk4 * 2] = w;
        }
        __syncthreads();
    }

    // epilogue: coil-combine with conj(smap), write partial [kz][2][x][y][t]
    float* po = part + (size_t)kz * 2 * NXY * NXY * NT;
#pragma unroll
    for (int mf = 0; mf < 4; ++mf) {
        const int y = ybase + 2 * mf + (quad >> 1);
        float or_ = 0.f, oi_ = 0.f;
#pragma unroll
        for (int r = 0; r < 4; ++r) {
            int c = 4 * (quad & 1) + r;
            float sr = csmap[(size_t)c * 2 * NXY * NXY + x * NXY + y];
            float si = csmap[(size_t)c * 2 * NXY * NXY + NXY * NXY + x * NXY + y];
            float xr = accr[mf][r], xi = acci[mf][r];
            or_ += sr * xr + si * xi;
            oi_ += sr * xi - si * xr;
        }
        or_ += __shfl_xor(or_, 16);
        oi_ += __shfl_xor(oi_, 16);
        if ((lane & 16) == 0) {
            po[(size_t)(x * NXY + y) * NT + t] = or_;
            po[(size_t)NXY * NXY * NT + (size_t)(x * NXY + y) * NT + t] = oi_;
        }
    }
}

// ---------------------------------------------------------------------------
// combine: out = part0 + part1 (elementwise over 2*128*128*16 floats)
// ---------------------------------------------------------------------------
__global__ __launch_bounds__(256) void combine(const float* __restrict__ part,
                                               float* __restrict__ out) {
    const int idx = blockIdx.x * 256 + threadIdx.x;      // < 524288
    out[idx] = part[idx] + part[idx + 2 * NXY * NXY * NT];
}

// ---------------------------------------------------------------------------
extern "C" void kernel_launch(void* const* d_in, const int* in_sizes, int n_in,
                              void* d_out, int out_size, void* d_ws, size_t ws_size,
                              hipStream_t stream) {
    const float* xin   = (const float*)d_in[0];  // (2,128,128,16)
    const float* ktraj = (const float*)d_in[1];  // (2,2048,16)
    const float* csmap = (const float*)d_in[2];  // (8,2,128,128)
    const float* dcomp = (const float*)d_in[3];  // (2048,16)
    float* out = (float*)d_out;                  // (2,128,128,16)

    // ws layout: ExC + ExB + EyT (16MB each) + srcB 8MB + g 2MB + part 4MB = 62MB
    const size_t TBL = (size_t)NT * NK * NXY;            // 4.19M dwords per table
    uint* ExC  = (uint*)d_ws;                            // [t][kt][xc][kp][xq]
    uint* ExB  = ExC + TBL;                              // [t][kg][x][kq]
    uint* EyT  = ExB + TBL;                              // [t][y][k]
    uint* srcB = EyT + TBL;                              // fragment-ordered
    float2* g  = (float2*)(srcB + (size_t)NT * NC * NXY * NXY);  // [t][k][c]
    float* part = (float*)(g + (size_t)NT * NK * NC);    // [kz2][2][x][y][t]

    prep_all<<<dim3(57344), 256, 0, stream>>>(ktraj, xin, csmap, ExC, ExB, EyT, srcB);
    fwd_gemm<<<dim3(NT, NC, 32), 256, 0, stream>>>(ExC, EyT, srcB, dcomp, g);
    adj_gemm<<<dim3(NT, NXY / 8, 2), 512, 0, stream>>>(ExB, EyT, g, csmap, part);
    combine<<<dim3(2048), 256, 0, stream>>>(part, out);
}

// Round 21
// 194.220 us; speedup vs baseline: 1.1538x; 1.0315x over previous
//
#include <hip/hip_runtime.h>

// Frame-wise E^H D E exact NDFT via separable phasors as two complex GEMMs on
// fp16 matrix cores (fp32 accumulate).
// v22 = v21 (200.3us best) + ONE isolated change: adj epilogue csmap access.
//  - csmapP[c][y][x] float2 (sr,si): the epilogue's 32 scalar loads at 512B
//    x-stride (64 trans/instr -> 2048 trans/wave, ~13us of adj) become 16
//    float2 loads with 16-lane x-contiguous runs (128 trans/wave, 16x cut).
//    Epilogue-only -> zero pipeline/re-sink risk. 1MB table built in prep_all.
//  - adj loop / kz=2 split / ExB / EyT / fwd / preps: v21 VERBATIM.

#define NT 16
#define NK 2048
#define NXY 128
#define NC 8

typedef _Float16 f16x8 __attribute__((ext_vector_type(8)));
typedef float f32x4 __attribute__((ext_vector_type(4)));

union F8 { f16x8 h; uint u[4]; };

#define MFMA16(a, b, c) __builtin_amdgcn_mfma_f32_16x16x32_f16((a), (b), (c), 0, 0, 0)

__device__ __forceinline__ uint pack2h(float a, float b) {
    union { _Float16 h[2]; uint u; } p;
    p.h[0] = (_Float16)a; p.h[1] = (_Float16)b;
    return p.u;
}
__device__ __forceinline__ float2 unpack2h(uint v) {
    union { uint u; _Float16 h[2]; } p;
    p.u = v;
    return make_float2((float)p.h[0], (float)p.h[1]);
}
__device__ __forceinline__ uint rot16(uint v) { return (v >> 16) | (v << 16); }

// ---------------------------------------------------------------------------
// prep_all: fused preps, branch on block range (block-uniform divergence).
//  [0, 16384):      phasA -> tiled ExC [t][kt16][xc8][kp128][xq16]
//  [16384, 32768):  phasB -> ExB [t][kg512][x128][kq4] (adj B fragments)
//  [32768, 49152):  phasC -> EyT [t][y128][k2048]
//  [49152, 57344):  src   -> srcB fragment order [t][c][ch8][mf8][r16][xl16]
//  [57344, 57856):  csmapP[c][y][x] = (csmap[c][0][x][y], csmap[c][1][x][y])
// ---------------------------------------------------------------------------
__global__ __launch_bounds__(256) void prep_all(const float* __restrict__ ktraj,
                                                const float* __restrict__ xin,
                                                const float* __restrict__ csmap,
                                                uint* __restrict__ ExC,
                                                uint* __restrict__ ExB,
                                                uint* __restrict__ EyT,
                                                uint* __restrict__ srcB,
                                                float2* __restrict__ csmapP) {
    const int b = blockIdx.x;
    const int tid = threadIdx.x;
    if (b < 16384) {
        // ---- phasA: ExC ----
        const int t = b >> 10;
        const int k = (b & 1023) * 2 + (tid >> 7);
        const int x = tid & 127;
        const float kx = ktraj[(size_t)k * NT + t];
        float s, c;
        __sincosf(-kx * (float)(x - 64), &s, &c);
        ExC[((size_t)(t * 16 + (k >> 7)) * 8 + (x >> 4)) * 2048 +
            (size_t)(k & 127) * 16 + (x & 15)] = pack2h(c, s);
    } else if (b < 32768) {
        // ---- phasB: ExB[t][kg][x][kq], idx linear = output linear ----
        const int idx = (b - 16384) * 256 + tid;     // < 4.19M
        const int kq = idx & 3, x = (idx >> 2) & 127, kg = (idx >> 9) & 511,
                  t = idx >> 18;
        const int kp = kg * 4 + kq;
        const float kx = ktraj[(size_t)kp * NT + t];
        float s, c;
        __sincosf(-kx * (float)(x - 64), &s, &c);
        ExB[idx] = pack2h(c, s);
    } else if (b < 49152) {
        // ---- phasC: EyT[t][y][k], idx linear = output linear ----
        const int idx = (b - 32768) * 256 + tid;     // < 4.19M
        const int k = idx & 2047, y = (idx >> 11) & 127, t = idx >> 18;
        const float ky = ktraj[(size_t)(NK + k) * NT + t];
        float s, c;
        __sincosf(-ky * (float)(y - 64), &s, &c);
        EyT[idx] = pack2h(c, s);
    } else if (b < 57344) {
        // ---- src ----
        const int idx = (b - 49152) * 256 + tid;   // < 2^21
        const int t = idx & 15, r = (idx >> 4) & 15, xl = (idx >> 8) & 15,
                  mf = (idx >> 12) & 7, ch = (idx >> 15) & 7, c = idx >> 18;
        const int x = ch * 16 + xl, y = mf * 16 + r;
        const float ir = xin[(size_t)(x * NXY + y) * NT + t];
        const float ii = xin[(size_t)NXY * NXY * NT + (size_t)(x * NXY + y) * NT + t];
        const float sr = csmap[(size_t)c * 2 * NXY * NXY + x * NXY + y];
        const float si = csmap[(size_t)c * 2 * NXY * NXY + NXY * NXY + x * NXY + y];
        srcB[((size_t)(t * NC + c) << 14) + ch * 2048 + mf * 256 + r * 16 + xl] =
            pack2h(sr * ir - si * ii, sr * ii + si * ir);
    } else {
        // ---- csmapP[c][y][x] ----
        const int idx = (b - 57344) * 256 + tid;   // < 131072
        const int x = idx & 127, y = (idx >> 7) & 127, c = idx >> 14;
        float2 v;
        v.x = csmap[(size_t)c * 2 * NXY * NXY + x * NXY + y];
        v.y = csmap[(size_t)c * 2 * NXY * NXY + NXY * NXY + x * NXY + y];
        csmapP[idx] = v;
    }
}

// ---------------------------------------------------------------------------
// fwd_gemm: block = (t, c, kt of 64 kpoints), 256 thr, 4 waves.  (v21 verbatim)
// Wave ws owns kp slice [kt*64 + ws*16, +16) and ALL 8 mf rows. 1 B-load per
// chunk per wave, B-side complex rotation. Epilogue reads EyT scalar dwords.
// ---------------------------------------------------------------------------
__global__ __launch_bounds__(256, 4) void fwd_gemm(const uint* __restrict__ ExC,
                                                   const uint* __restrict__ EyT,
                                                   const uint* __restrict__ srcB,
                                                   const float* __restrict__ dcomp,
                                                   float2* __restrict__ g) {
    const int t = blockIdx.x, c = blockIdx.y, kt = blockIdx.z;
    const int tid = threadIdx.x, lane = tid & 63, ws = tid >> 6;
    const int quad = lane >> 4, l15 = lane & 15;

    __shared__ __align__(16) _Float16 As[2][4096];

    f32x4 accr[8], acci[8];
#pragma unroll
    for (int mf = 0; mf < 8; ++mf) { accr[mf] = (f32x4)0.0f; acci[mf] = (f32x4)0.0f; }

    const uint* srcT = srcB + ((size_t)(t * NC + c) << 14);
    const uint* exB = ExC + (size_t)(t * 16 + (kt >> 1)) * 16384;
    const int kin0 = (kt & 1) * 64 + ws * 16;            // this wave's kp base (128-tile)

    // prologue: stage + B load for chunk 0
    F8 vA0 = *(const F8*)(srcT + tid * 8);
    F8 vA1 = *(const F8*)(srcT + tid * 8 + 4);
    F8 Bc = *(const F8*)(exB + (kin0 + l15) * 16 + quad * 4);

#pragma unroll 2
    for (int ch = 0; ch < 8; ++ch) {
        const int buf = ch & 1;
        *(F8*)&As[buf][tid * 16] = vA0;
        *(F8*)&As[buf][tid * 16 + 8] = vA1;
        __syncthreads();
        const int chn = ch < 7 ? ch + 1 : 7;
        vA0 = *(const F8*)(srcT + chn * 2048 + tid * 8);
        vA1 = *(const F8*)(srcT + chn * 2048 + tid * 8 + 4);
        F8 Bn = *(const F8*)(exB + chn * 2048 + (kin0 + l15) * 16 + quad * 4);
        __builtin_amdgcn_sched_barrier(0);
        // B-side rotation: Br = (bR,-bI) for real part, Bi = (bI,bR) for imag
        F8 Br, Bi;
#pragma unroll
        for (int d = 0; d < 4; ++d) {
            Br.u[d] = Bc.u[d] ^ 0x80000000u;
            Bi.u[d] = rot16(Bc.u[d]);
        }
#pragma unroll
        for (int mf = 0; mf < 8; ++mf) {
            F8 Ap = *(const F8*)&As[buf][mf * 512 + l15 * 32 + quad * 8];
            accr[mf] = MFMA16(Ap.h, Br.h, accr[mf]);
            acci[mf] = MFMA16(Ap.h, Bi.h, acci[mf]);
        }
        Bc = Bn;
    }

    // epilogue: in-wave y-reduction with EyT (scalar dword reads), quad-reduce
    const int kpoint = kt * 64 + ws * 16 + l15;
    const uint* eyK = EyT + (size_t)t * 262144 + kpoint;   // per-lane col base
    float kdr = 0.f, kdi = 0.f;
#pragma unroll
    for (int mf = 0; mf < 8; ++mf) {
#pragma unroll
        for (int rr = 0; rr < 4; ++rr) {
            const int y = mf * 16 + quad * 4 + rr;
            float2 ey = unpack2h(eyK[(size_t)y * 2048]);
            float cr = accr[mf][rr], ci = acci[mf][rr];
            kdr += ey.x * cr - ey.y * ci;
            kdi += ey.x * ci + ey.y * cr;
        }
    }
    kdr += __shfl_xor(kdr, 16); kdr += __shfl_xor(kdr, 32);
    kdi += __shfl_xor(kdi, 16); kdi += __shfl_xor(kdi, 32);
    if (lane < 16) {
        float w = dcomp[(size_t)kpoint * NT + t] * (1.0f / 16384.0f);
        g[((size_t)t * NK + kpoint) * NC + c] = make_float2(kdr * w, kdi * w);
    }
}

// ---------------------------------------------------------------------------
// adj_gemm: block = (t, ytile of 8 y, kz of 2 k-halves), 512 thr (8 waves).
// Each block: 32 chunks of 32 kpoints. Disjoint reads, private f32 partials.
// v21 body; ONLY the epilogue csmap access changed: csmapP[c][y][x] float2
// -> 16-lane x-contiguous 128B runs (2048 -> 128 trans/wave-epilogue).
// ---------------------------------------------------------------------------
__global__ __launch_bounds__(512) void adj_gemm(const uint* __restrict__ ExB,
                                                const uint* __restrict__ EyT,
                                                const float2* __restrict__ g,
                                                const float2* __restrict__ csmapP,
                                                float* __restrict__ part) {
    const int t = blockIdx.x, yt = blockIdx.y, kz = blockIdx.z, ybase = yt * 8;
    const int tid = threadIdx.x, lane = tid & 63, ws = tid >> 6;
    const int quad = lane >> 4, l15 = lane & 15;
    const int x = ws * 16 + l15;
    const int kbase = kz * 1024;

    __shared__ __align__(16) _Float16 Ts[2][64][72];    // 64 K'-halves + 8 pad

    f32x4 accr[4], acci[4];
#pragma unroll
    for (int mf = 0; mf < 4; ++mf) { accr[mf] = (f32x4)0.0f; acci[mf] = (f32x4)0.0f; }

    const float2* gBase = g + (size_t)t * NK * NC;
    // ExB fragment base for this lane: row (kg, x) -> 4 dwords.
    const uint* exFrag = ExB + (size_t)t * 262144 +
                         ((size_t)(kbase >> 2) + quad) * 512 + (size_t)x * 4;

    const int bm = tid & 63;                 // build: row m
    const int bk4 = (tid >> 6) * 4;          // build: kpoint offset (0..28)
    const int by = ybase + (bm >> 3), bc = bm & 7;
    const uint* eyRow = EyT + (size_t)t * 262144 + (size_t)by * 2048;  // per-thread row

    // build chunk 0
    {
        F8 w;
#pragma unroll
        for (int j = 0; j < 4; ++j) {
            int kp = kbase + bk4 + j;
            float2 gv = gBase[kp * NC + bc];
            float2 ey = unpack2h(eyRow[kp]);
            w.u[j] = pack2h(ey.x * gv.x + ey.y * gv.y, ey.x * gv.y - ey.y * gv.x);
        }
        *(F8*)&Ts[0][bm][bk4 * 2] = w;
    }
    __syncthreads();

    for (int ch = 0; ch < 32; ++ch) {
        const int buf = ch & 1;
        const int chn = ch < 31 ? ch + 1 : 31;       // clamped: last iter redundant
        // --- B loads FIRST (fragment-contiguous; consumed first) ---
        F8 Bf0 = *(const F8*)(exFrag + (size_t)ch * 4096);
        F8 Bf1 = *(const F8*)(exFrag + (size_t)ch * 4096 + 2048);
        // --- then build loads for chunk ch+1 (consumed after MFMA phase) ---
        const int kb = kbase + chn * 32 + bk4;
        float2 gv0 = gBase[(kb + 0) * NC + bc];
        float2 gv1 = gBase[(kb + 1) * NC + bc];
        float2 gv2 = gBase[(kb + 2) * NC + bc];
        float2 gv3 = gBase[(kb + 3) * NC + bc];
        uint ev0 = eyRow[kb + 0];
        uint ev1 = eyRow[kb + 1];
        uint ev2 = eyRow[kb + 2];
        uint ev3 = eyRow[kb + 3];
        __builtin_amdgcn_sched_barrier(0);
        // B-side rotation for imag accumulator: Bi = (-bI, bR)
        F8 Bi0, Bi1;
#pragma unroll
        for (int d = 0; d < 4; ++d) {
            Bi0.u[d] = rot16(Bf0.u[d]) ^ 0x00008000u;
            Bi1.u[d] = rot16(Bf1.u[d]) ^ 0x00008000u;
        }
        // --- MFMA phase on Ts[buf] ---
#pragma unroll
        for (int mf = 0; mf < 4; ++mf) {
            F8 Ap0 = *(const F8*)&Ts[buf][mf * 16 + l15][quad * 8];
            accr[mf] = MFMA16(Ap0.h, Bf0.h, accr[mf]);
            acci[mf] = MFMA16(Ap0.h, Bi0.h, acci[mf]);
            F8 Ap1 = *(const F8*)&Ts[buf][mf * 16 + l15][32 + quad * 8];
            accr[mf] = MFMA16(Ap1.h, Bf1.h, accr[mf]);
            acci[mf] = MFMA16(Ap1.h, Bi1.h, acci[mf]);
        }
        // --- pack + write build for chunk ch+1 ---
        {
            F8 w; float2 e;
            e = unpack2h(ev0); w.u[0] = pack2h(e.x*gv0.x + e.y*gv0.y, e.x*gv0.y - e.y*gv0.x);
            e = unpack2h(ev1); w.u[1] = pack2h(e.x*gv1.x + e.y*gv1.y, e.x*gv1.y - e.y*gv1.x);
            e = unpack2h(ev2); w.u[2] = pack2h(e.x*gv2.x + e.y*gv2.y, e.x*gv2.y - e.y*gv2.x);
            e = unpack2h(ev3); w.u[3] = pack2h(e.x*gv3.x + e.y*gv3.y, e.x*gv3.y - e.y*gv3.x);
            *(F8*)&Ts[buf ^ 1][bm][bk4 * 2] = w;
        }
        __syncthreads();
    }

    // epilogue: coil-combine with conj(smap) via csmapP, partial [kz][2][x][y][t]
    float* po = part + (size_t)kz * 2 * NXY * NXY * NT;
#pragma unroll
    for (int mf = 0; mf < 4; ++mf) {
        const int y = ybase + 2 * mf + (quad >> 1);
        float or_ = 0.f, oi_ = 0.f;
#pragma unroll
        for (int r = 0; r < 4; ++r) {
            int c = 4 * (quad & 1) + r;
            float2 sm = csmapP[(size_t)c * NXY * NXY + y * NXY + x];
            float xr = accr[mf][r], xi = acci[mf][r];
            or_ += sm.x * xr + sm.y * xi;
            oi_ += sm.x * xi - sm.y * xr;
        }
        or_ += __shfl_xor(or_, 16);
        oi_ += __shfl_xor(oi_, 16);
        if ((lane & 16) == 0) {
            po[(size_t)(x * NXY + y) * NT + t] = or_;
            po[(size_t)NXY * NXY * NT + (size_t)(x * NXY + y) * NT + t] = oi_;
        }
    }
}

// ---------------------------------------------------------------------------
// combine: out = part0 + part1 (elementwise over 2*128*128*16 floats)
// ---------------------------------------------------------------------------
__global__ __launch_bounds__(256) void combine(const float* __restrict__ part,
                                               float* __restrict__ out) {
    const int idx = blockIdx.x * 256 + threadIdx.x;      // < 524288
    out[idx] = part[idx] + part[idx + 2 * NXY * NXY * NT];
}

// ---------------------------------------------------------------------------
extern "C" void kernel_launch(void* const* d_in, const int* in_sizes, int n_in,
                              void* d_out, int out_size, void* d_ws, size_t ws_size,
                              hipStream_t stream) {
    const float* xin   = (const float*)d_in[0];  // (2,128,128,16)
    const float* ktraj = (const float*)d_in[1];  // (2,2048,16)
    const float* csmap = (const float*)d_in[2];  // (8,2,128,128)
    const float* dcomp = (const float*)d_in[3];  // (2048,16)
    float* out = (float*)d_out;                  // (2,128,128,16)

    // ws: ExC+ExB+EyT (16MB each) + srcB 8MB + g 2MB + part 4MB + csmapP 1MB = 63MB
    const size_t TBL = (size_t)NT * NK * NXY;            // 4.19M dwords per table
    uint* ExC  = (uint*)d_ws;                            // [t][kt][xc][kp][xq]
    uint* ExB  = ExC + TBL;                              // [t][kg][x][kq]
    uint* EyT  = ExB + TBL;                              // [t][y][k]
    uint* srcB = EyT + TBL;                              // fragment-ordered
    float2* g  = (float2*)(srcB + (size_t)NT * NC * NXY * NXY);  // [t][k][c]
    float* part = (float*)(g + (size_t)NT * NK * NC);    // [kz2][2][x][y][t]
    float2* csmapP = (float2*)(part + (size_t)4 * NXY * NXY * NT);  // [c][y][x]

    prep_all<<<dim3(57856), 256, 0, stream>>>(ktraj, xin, csmap, ExC, ExB, EyT, srcB, csmapP);
    fwd_gemm<<<dim3(NT, NC, 32), 256, 0, stream>>>(ExC, EyT, srcB, dcomp, g);
    adj_gemm<<<dim3(NT, NXY / 8, 2), 512, 0, stream>>>(ExB, EyT, g, csmapP, part);
    combine<<<dim3(2048), 256, 0, stream>>>(part, out);
}

// Round 22
// 188.242 us; speedup vs baseline: 1.1904x; 1.0318x over previous
//
#include <hip/hip_runtime.h>

// Frame-wise E^H D E exact NDFT via separable phasors as two complex GEMMs on
// fp16 matrix cores (fp32 accumulate).
// v23 = v22 (194.2us best) + ONE isolated change: adj B prefetch 1 chunk ahead
// (fwd's proven Bc/Bn register-rotation idiom; removes the ~200-400cy L2 wait
// between B load and its rot16 consumer from every chunk's critical path).
// Addressing linear (exFrag + ch*4096) -> no re-sink trigger; +8 VGPR only.
//  - adj build / kz=2 split / ExB / EyT / csmapP epilogue / fwd / preps:
//    v22 VERBATIM.

#define NT 16
#define NK 2048
#define NXY 128
#define NC 8

typedef _Float16 f16x8 __attribute__((ext_vector_type(8)));
typedef float f32x4 __attribute__((ext_vector_type(4)));

union F8 { f16x8 h; uint u[4]; };

#define MFMA16(a, b, c) __builtin_amdgcn_mfma_f32_16x16x32_f16((a), (b), (c), 0, 0, 0)

__device__ __forceinline__ uint pack2h(float a, float b) {
    union { _Float16 h[2]; uint u; } p;
    p.h[0] = (_Float16)a; p.h[1] = (_Float16)b;
    return p.u;
}
__device__ __forceinline__ float2 unpack2h(uint v) {
    union { uint u; _Float16 h[2]; } p;
    p.u = v;
    return make_float2((float)p.h[0], (float)p.h[1]);
}
__device__ __forceinline__ uint rot16(uint v) { return (v >> 16) | (v << 16); }

// ---------------------------------------------------------------------------
// prep_all: fused preps, branch on block range (block-uniform divergence).
//  [0, 16384):      phasA -> tiled ExC [t][kt16][xc8][kp128][xq16]
//  [16384, 32768):  phasB -> ExB [t][kg512][x128][kq4] (adj B fragments)
//  [32768, 49152):  phasC -> EyT [t][y128][k2048]
//  [49152, 57344):  src   -> srcB fragment order [t][c][ch8][mf8][r16][xl16]
//  [57344, 57856):  csmapP[c][y][x] = (csmap[c][0][x][y], csmap[c][1][x][y])
// ---------------------------------------------------------------------------
__global__ __launch_bounds__(256) void prep_all(const float* __restrict__ ktraj,
                                                const float* __restrict__ xin,
                                                const float* __restrict__ csmap,
                                                uint* __restrict__ ExC,
                                                uint* __restrict__ ExB,
                                                uint* __restrict__ EyT,
                                                uint* __restrict__ srcB,
                                                float2* __restrict__ csmapP) {
    const int b = blockIdx.x;
    const int tid = threadIdx.x;
    if (b < 16384) {
        // ---- phasA: ExC ----
        const int t = b >> 10;
        const int k = (b & 1023) * 2 + (tid >> 7);
        const int x = tid & 127;
        const float kx = ktraj[(size_t)k * NT + t];
        float s, c;
        __sincosf(-kx * (float)(x - 64), &s, &c);
        ExC[((size_t)(t * 16 + (k >> 7)) * 8 + (x >> 4)) * 2048 +
            (size_t)(k & 127) * 16 + (x & 15)] = pack2h(c, s);
    } else if (b < 32768) {
        // ---- phasB: ExB[t][kg][x][kq], idx linear = output linear ----
        const int idx = (b - 16384) * 256 + tid;     // < 4.19M
        const int kq = idx & 3, x = (idx >> 2) & 127, kg = (idx >> 9) & 511,
                  t = idx >> 18;
        const int kp = kg * 4 + kq;
        const float kx = ktraj[(size_t)kp * NT + t];
        float s, c;
        __sincosf(-kx * (float)(x - 64), &s, &c);
        ExB[idx] = pack2h(c, s);
    } else if (b < 49152) {
        // ---- phasC: EyT[t][y][k], idx linear = output linear ----
        const int idx = (b - 32768) * 256 + tid;     // < 4.19M
        const int k = idx & 2047, y = (idx >> 11) & 127, t = idx >> 18;
        const float ky = ktraj[(size_t)(NK + k) * NT + t];
        float s, c;
        __sincosf(-ky * (float)(y - 64), &s, &c);
        EyT[idx] = pack2h(c, s);
    } else if (b < 57344) {
        // ---- src ----
        const int idx = (b - 49152) * 256 + tid;   // < 2^21
        const int t = idx & 15, r = (idx >> 4) & 15, xl = (idx >> 8) & 15,
                  mf = (idx >> 12) & 7, ch = (idx >> 15) & 7, c = idx >> 18;
        const int x = ch * 16 + xl, y = mf * 16 + r;
        const float ir = xin[(size_t)(x * NXY + y) * NT + t];
        const float ii = xin[(size_t)NXY * NXY * NT + (size_t)(x * NXY + y) * NT + t];
        const float sr = csmap[(size_t)c * 2 * NXY * NXY + x * NXY + y];
        const float si = csmap[(size_t)c * 2 * NXY * NXY + NXY * NXY + x * NXY + y];
        srcB[((size_t)(t * NC + c) << 14) + ch * 2048 + mf * 256 + r * 16 + xl] =
            pack2h(sr * ir - si * ii, sr * ii + si * ir);
    } else {
        // ---- csmapP[c][y][x] ----
        const int idx = (b - 57344) * 256 + tid;   // < 131072
        const int x = idx & 127, y = (idx >> 7) & 127, c = idx >> 14;
        float2 v;
        v.x = csmap[(size_t)c * 2 * NXY * NXY + x * NXY + y];
        v.y = csmap[(size_t)c * 2 * NXY * NXY + NXY * NXY + x * NXY + y];
        csmapP[idx] = v;
    }
}

// ---------------------------------------------------------------------------
// fwd_gemm: block = (t, c, kt of 64 kpoints), 256 thr, 4 waves.  (v22 verbatim)
// Wave ws owns kp slice [kt*64 + ws*16, +16) and ALL 8 mf rows. 1 B-load per
// chunk per wave, B-side complex rotation. Epilogue reads EyT scalar dwords.
// ---------------------------------------------------------------------------
__global__ __launch_bounds__(256, 4) void fwd_gemm(const uint* __restrict__ ExC,
                                                   const uint* __restrict__ EyT,
                                                   const uint* __restrict__ srcB,
                                                   const float* __restrict__ dcomp,
                                                   float2* __restrict__ g) {
    const int t = blockIdx.x, c = blockIdx.y, kt = blockIdx.z;
    const int tid = threadIdx.x, lane = tid & 63, ws = tid >> 6;
    const int quad = lane >> 4, l15 = lane & 15;

    __shared__ __align__(16) _Float16 As[2][4096];

    f32x4 accr[8], acci[8];
#pragma unroll
    for (int mf = 0; mf < 8; ++mf) { accr[mf] = (f32x4)0.0f; acci[mf] = (f32x4)0.0f; }

    const uint* srcT = srcB + ((size_t)(t * NC + c) << 14);
    const uint* exB = ExC + (size_t)(t * 16 + (kt >> 1)) * 16384;
    const int kin0 = (kt & 1) * 64 + ws * 16;            // this wave's kp base (128-tile)

    // prologue: stage + B load for chunk 0
    F8 vA0 = *(const F8*)(srcT + tid * 8);
    F8 vA1 = *(const F8*)(srcT + tid * 8 + 4);
    F8 Bc = *(const F8*)(exB + (kin0 + l15) * 16 + quad * 4);

#pragma unroll 2
    for (int ch = 0; ch < 8; ++ch) {
        const int buf = ch & 1;
        *(F8*)&As[buf][tid * 16] = vA0;
        *(F8*)&As[buf][tid * 16 + 8] = vA1;
        __syncthreads();
        const int chn = ch < 7 ? ch + 1 : 7;
        vA0 = *(const F8*)(srcT + chn * 2048 + tid * 8);
        vA1 = *(const F8*)(srcT + chn * 2048 + tid * 8 + 4);
        F8 Bn = *(const F8*)(exB + chn * 2048 + (kin0 + l15) * 16 + quad * 4);
        __builtin_amdgcn_sched_barrier(0);
        // B-side rotation: Br = (bR,-bI) for real part, Bi = (bI,bR) for imag
        F8 Br, Bi;
#pragma unroll
        for (int d = 0; d < 4; ++d) {
            Br.u[d] = Bc.u[d] ^ 0x80000000u;
            Bi.u[d] = rot16(Bc.u[d]);
        }
#pragma unroll
        for (int mf = 0; mf < 8; ++mf) {
            F8 Ap = *(const F8*)&As[buf][mf * 512 + l15 * 32 + quad * 8];
            accr[mf] = MFMA16(Ap.h, Br.h, accr[mf]);
            acci[mf] = MFMA16(Ap.h, Bi.h, acci[mf]);
        }
        Bc = Bn;
    }

    // epilogue: in-wave y-reduction with EyT (scalar dword reads), quad-reduce
    const int kpoint = kt * 64 + ws * 16 + l15;
    const uint* eyK = EyT + (size_t)t * 262144 + kpoint;   // per-lane col base
    float kdr = 0.f, kdi = 0.f;
#pragma unroll
    for (int mf = 0; mf < 8; ++mf) {
#pragma unroll
        for (int rr = 0; rr < 4; ++rr) {
            const int y = mf * 16 + quad * 4 + rr;
            float2 ey = unpack2h(eyK[(size_t)y * 2048]);
            float cr = accr[mf][rr], ci = acci[mf][rr];
            kdr += ey.x * cr - ey.y * ci;
            kdi += ey.x * ci + ey.y * cr;
        }
    }
    kdr += __shfl_xor(kdr, 16); kdr += __shfl_xor(kdr, 32);
    kdi += __shfl_xor(kdi, 16); kdi += __shfl_xor(kdi, 32);
    if (lane < 16) {
        float w = dcomp[(size_t)kpoint * NT + t] * (1.0f / 16384.0f);
        g[((size_t)t * NK + kpoint) * NC + c] = make_float2(kdr * w, kdi * w);
    }
}

// ---------------------------------------------------------------------------
// adj_gemm: block = (t, ytile of 8 y, kz of 2 k-halves), 512 thr (8 waves).
// Each block: 32 chunks of 32 kpoints. Disjoint reads, private f32 partials.
// v22 body; ONE change: B prefetched one chunk ahead (Bc/Bn rotation, fwd's
// proven idiom) -> the B->rot16 L2 wait leaves the per-chunk critical path.
// ---------------------------------------------------------------------------
__global__ __launch_bounds__(512) void adj_gemm(const uint* __restrict__ ExB,
                                                const uint* __restrict__ EyT,
                                                const float2* __restrict__ g,
                                                const float2* __restrict__ csmapP,
                                                float* __restrict__ part) {
    const int t = blockIdx.x, yt = blockIdx.y, kz = blockIdx.z, ybase = yt * 8;
    const int tid = threadIdx.x, lane = tid & 63, ws = tid >> 6;
    const int quad = lane >> 4, l15 = lane & 15;
    const int x = ws * 16 + l15;
    const int kbase = kz * 1024;

    __shared__ __align__(16) _Float16 Ts[2][64][72];    // 64 K'-halves + 8 pad

    f32x4 accr[4], acci[4];
#pragma unroll
    for (int mf = 0; mf < 4; ++mf) { accr[mf] = (f32x4)0.0f; acci[mf] = (f32x4)0.0f; }

    const float2* gBase = g + (size_t)t * NK * NC;
    // ExB fragment base for this lane: row (kg, x) -> 4 dwords.
    const uint* exFrag = ExB + (size_t)t * 262144 +
                         ((size_t)(kbase >> 2) + quad) * 512 + (size_t)x * 4;

    const int bm = tid & 63;                 // build: row m
    const int bk4 = (tid >> 6) * 4;          // build: kpoint offset (0..28)
    const int by = ybase + (bm >> 3), bc = bm & 7;
    const uint* eyRow = EyT + (size_t)t * 262144 + (size_t)by * 2048;  // per-thread row

    // build chunk 0; prefetch B for chunk 0
    {
        F8 w;
#pragma unroll
        for (int j = 0; j < 4; ++j) {
            int kp = kbase + bk4 + j;
            float2 gv = gBase[kp * NC + bc];
            float2 ey = unpack2h(eyRow[kp]);
            w.u[j] = pack2h(ey.x * gv.x + ey.y * gv.y, ey.x * gv.y - ey.y * gv.x);
        }
        *(F8*)&Ts[0][bm][bk4 * 2] = w;
    }
    F8 Bc0 = *(const F8*)(exFrag);
    F8 Bc1 = *(const F8*)(exFrag + 2048);
    __syncthreads();

    for (int ch = 0; ch < 32; ++ch) {
        const int buf = ch & 1;
        const int chn = ch < 31 ? ch + 1 : 31;       // clamped: last iter redundant
        // --- issue next-chunk B loads (consumed next iteration) ---
        F8 Bn0 = *(const F8*)(exFrag + (size_t)chn * 4096);
        F8 Bn1 = *(const F8*)(exFrag + (size_t)chn * 4096 + 2048);
        // --- build loads for chunk ch+1 (consumed after MFMA phase) ---
        const int kb = kbase + chn * 32 + bk4;
        float2 gv0 = gBase[(kb + 0) * NC + bc];
        float2 gv1 = gBase[(kb + 1) * NC + bc];
        float2 gv2 = gBase[(kb + 2) * NC + bc];
        float2 gv3 = gBase[(kb + 3) * NC + bc];
        uint ev0 = eyRow[kb + 0];
        uint ev1 = eyRow[kb + 1];
        uint ev2 = eyRow[kb + 2];
        uint ev3 = eyRow[kb + 3];
        __builtin_amdgcn_sched_barrier(0);
        // B-side rotation for imag accumulator (B from LAST iteration's load)
        F8 Bi0, Bi1;
#pragma unroll
        for (int d = 0; d < 4; ++d) {
            Bi0.u[d] = rot16(Bc0.u[d]) ^ 0x00008000u;
            Bi1.u[d] = rot16(Bc1.u[d]) ^ 0x00008000u;
        }
        // --- MFMA phase on Ts[buf] ---
#pragma unroll
        for (int mf = 0; mf < 4; ++mf) {
            F8 Ap0 = *(const F8*)&Ts[buf][mf * 16 + l15][quad * 8];
            accr[mf] = MFMA16(Ap0.h, Bc0.h, accr[mf]);
            acci[mf] = MFMA16(Ap0.h, Bi0.h, acci[mf]);
            F8 Ap1 = *(const F8*)&Ts[buf][mf * 16 + l15][32 + quad * 8];
            accr[mf] = MFMA16(Ap1.h, Bc1.h, accr[mf]);
            acci[mf] = MFMA16(Ap1.h, Bi1.h, acci[mf]);
        }
        // --- pack + write build for chunk ch+1 ---
        {
            F8 w; float2 e;
            e = unpack2h(ev0); w.u[0] = pack2h(e.x*gv0.x + e.y*gv0.y, e.x*gv0.y - e.y*gv0.x);
            e = unpack2h(ev1); w.u[1] = pack2h(e.x*gv1.x + e.y*gv1.y, e.x*gv1.y - e.y*gv1.x);
            e = unpack2h(ev2); w.u[2] = pack2h(e.x*gv2.x + e.y*gv2.y, e.x*gv2.y - e.y*gv2.x);
            e = unpack2h(ev3); w.u[3] = pack2h(e.x*gv3.x + e.y*gv3.y, e.x*gv3.y - e.y*gv3.x);
            *(F8*)&Ts[buf ^ 1][bm][bk4 * 2] = w;
        }
        // rotate B prefetch registers
        Bc0 = Bn0; Bc1 = Bn1;
        __syncthreads();
    }

    // epilogue: coil-combine with conj(smap) via csmapP, partial [kz][2][x][y][t]
    float* po = part + (size_t)kz * 2 * NXY * NXY * NT;
#pragma unroll
    for (int mf = 0; mf < 4; ++mf) {
        const int y = ybase + 2 * mf + (quad >> 1);
        float or_ = 0.f, oi_ = 0.f;
#pragma unroll
        for (int r = 0; r < 4; ++r) {
            int c = 4 * (quad & 1) + r;
            float2 sm = csmapP[(size_t)c * NXY * NXY + y * NXY + x];
            float xr = accr[mf][r], xi = acci[mf][r];
            or_ += sm.x * xr + sm.y * xi;
            oi_ += sm.x * xi - sm.y * xr;
        }
        or_ += __shfl_xor(or_, 16);
        oi_ += __shfl_xor(oi_, 16);
        if ((lane & 16) == 0) {
            po[(size_t)(x * NXY + y) * NT + t] = or_;
            po[(size_t)NXY * NXY * NT + (size_t)(x * NXY + y) * NT + t] = oi_;
        }
    }
}

// ---------------------------------------------------------------------------
// combine: out = part0 + part1 (elementwise over 2*128*128*16 floats)
// ---------------------------------------------------------------------------
__global__ __launch_bounds__(256) void combine(const float* __restrict__ part,
                                               float* __restrict__ out) {
    const int idx = blockIdx.x * 256 + threadIdx.x;      // < 524288
    out[idx] = part[idx] + part[idx + 2 * NXY * NXY * NT];
}

// ---------------------------------------------------------------------------
extern "C" void kernel_launch(void* const* d_in, const int* in_sizes, int n_in,
                              void* d_out, int out_size, void* d_ws, size_t ws_size,
                              hipStream_t stream) {
    const float* xin   = (const float*)d_in[0];  // (2,128,128,16)
    const float* ktraj = (const float*)d_in[1];  // (2,2048,16)
    const float* csmap = (const float*)d_in[2];  // (8,2,128,128)
    const float* dcomp = (const float*)d_in[3];  // (2048,16)
    float* out = (float*)d_out;                  // (2,128,128,16)

    // ws: ExC+ExB+EyT (16MB each) + srcB 8MB + g 2MB + part 4MB + csmapP 1MB = 63MB
    const size_t TBL = (size_t)NT * NK * NXY;            // 4.19M dwords per table
    uint* ExC  = (uint*)d_ws;                            // [t][kt][xc][kp][xq]
    uint* ExB  = ExC + TBL;                              // [t][kg][x][kq]
    uint* EyT  = ExB + TBL;                              // [t][y][k]
    uint* srcB = EyT + TBL;                              // fragment-ordered
    float2* g  = (float2*)(srcB + (size_t)NT * NC * NXY * NXY);  // [t][k][c]
    float* part = (float*)(g + (size_t)NT * NK * NC);    // [kz2][2][x][y][t]
    float2* csmapP = (float2*)(part + (size_t)4 * NXY * NXY * NT);  // [c][y][x]

    prep_all<<<dim3(57856), 256, 0, stream>>>(ktraj, xin, csmap, ExC, ExB, EyT, srcB, csmapP);
    fwd_gemm<<<dim3(NT, NC, 32), 256, 0, stream>>>(ExC, EyT, srcB, dcomp, g);
    adj_gemm<<<dim3(NT, NXY / 8, 2), 512, 0, stream>>>(ExB, EyT, g, csmapP, part);
    combine<<<dim3(2048), 256, 0, stream>>>(part, out);
}